// Round 8
// baseline (423.760 us; speedup 1.0000x reference)
//
#include <hip/hip_runtime.h>
#include <math.h>

// Problem constants (from reference setup_inputs)
#define NN    5000      // nodes
#define NE    80000     // edges
#define NB    32        // batch
#define DIN   16        // input feat
#define CH    64        // conv channels
#define KPOOL 30
#define FTOT  208      // 16 + 3*64
#define FLATW 6241     // KPOOL*FTOT + 1
#define NH    128      // MLP hidden
#define NG    8        // batch groups (one per XCD)
#define GB    4        // batches per group
#define NPB   16       // nodes per block (4 per wave)
#define NCHUNK 313     // node chunks (blocks per group)
#define NPAD  5008     // perm array size (grid covers 313*16)
#define NEPAD (NE + 4 * NN)   // CSR rows padded to multiple of 4
#define NSLOT 32       // stats atomic-spread slots

// Journal: R19 ordering / R20+R24 occupancy: dead (layers latency-bound, not
// wave-count-bound). R21 CSR rotate: neutral. R22 act-hoist: -43% VALU ->
// -5% dur (memory-bound proof); inline act optimal. R26 serial-merge
// (phase1 roles, bnfin->toppool, wide head2): 354 -> 348.6, layers unchanged.
// R27/R28: CIN64 per-XCD gather footprint 5.12MB > 4MB L2 (FETCH 114MB vs
// 42MB compulsory = miss re-fetch). Split each CIN64 layer into TWO batch-half
// kernels (bi 0-1 / 2-3): 512B rows, 2.56MB footprint fits L2. float2 lanes
// (64 x 8B = one row), o[2] stage-2, NT stores keep writes from evicting the
// resident input. R28 fixes R27's compile error: nontemporal builtin needs a
// NATIVE vector type, not HIP float4 — route via ext_vector_type(4).
// Canary: FETCH per half ~25-40MB = win; ~55MB = no L2 gain -> fp32 gather
// floor confirmed, pivot to tail.

// ---------------- setup kernels ----------------

__global__ void k_init(float* deg, int* counts, float* stats, float* hm, int* perm) {
    int i = blockIdx.x * 256 + threadIdx.x;
    if (i < NN) { deg[i] = 1.0f; counts[i] = 0; }   // deg starts at self-loop value 1
    if (i < 2 * NSLOT * 128) stats[i] = 0.0f;       // [2 layers][32 slots][128]
    if (i < 4096) hm[i] = 0.0f;
    if (i >= NN && i < NPAD) perm[i] = NN;          // tail -> invalid marker
}

#define NEB 313
__global__ void k_edges(const float* __restrict__ attr, const int* __restrict__ erow,
                        float* deg, int* counts) {
    int e = blockIdx.x * 256 + threadIdx.x;
    if (e < NE) {
        int r = erow[e];
        atomicAdd(&deg[r], attr[e]);
        atomicAdd(&counts[r], 1);
    }
}

// merged concurrent phase: block 0 = prefix scan, block 1 = counting sort,
// blocks 2.. = x transpose (serial roles hide under the wide transpose).
__global__ __launch_bounds__(1024) void k_phase1(
        const int* __restrict__ counts, const float* __restrict__ deg,
        int* rowptr, int* cursor, float* dinv, int* perm,
        const float* __restrict__ x, float* __restrict__ xt) {
    __shared__ int wsum[16], woff[16];
    __shared__ int carry_sh;
    __shared__ int hist[256];
    int t = threadIdx.x;
    if (blockIdx.x >= 2) {
        int idx = (blockIdx.x - 2) * 1024 + t;
        if (idx >= NB * NN) return;
        int b = idx / NN, n = idx % NN;
        int g = b >> 2, bi = b & 3;
        const float4* src = (const float4*)(x + (size_t)idx * DIN);
        float4* dst = (float4*)(xt + (((size_t)g * NN + n) * GB + bi) * DIN);
        dst[0] = src[0]; dst[1] = src[1]; dst[2] = src[2]; dst[3] = src[3];
        return;
    }
    if (blockIdx.x == 0) {
        int lane = t & 63, wid = t >> 6;
        if (t == 0) carry_sh = 0;
        __syncthreads();
        for (int base = 0; base < NN; base += 1024) {
            int carry = carry_sh;
            int i = base + t;
            int v = 0;
            if (i < NN) {
                v = (counts[i] + 3) & ~3;
                dinv[i] = 1.0f / sqrtf(deg[i]);   // deg >= 1 always
            }
            int s = v;
#pragma unroll
            for (int off = 1; off < 64; off <<= 1) {
                int o = __shfl_up(s, off);
                if (lane >= off) s += o;
            }
            if (lane == 63) wsum[wid] = s;
            __syncthreads();
            if (t < 16) {
                int w = wsum[t];
#pragma unroll
                for (int off = 1; off < 16; off <<= 1) {
                    int o = __shfl_up(w, off);
                    if (t >= off) w += o;
                }
                woff[t] = w;
            }
            __syncthreads();
            int inc = s + (wid > 0 ? woff[wid - 1] : 0) + carry;
            if (i < NN) {
                rowptr[i + 1] = inc;
                cursor[i] = inc - v;
            }
            if (t == 1023) carry_sh = carry + woff[15];
            __syncthreads();
        }
        if (t == 0) rowptr[0] = 0;
    } else {
        if (t < 256) hist[t] = 0;
        __syncthreads();
        for (int i = t; i < NN; i += 1024) {
            int b = 255 - min(((counts[i] + 3) & ~3) >> 2, 255);
            atomicAdd(&hist[b], 1);
        }
        __syncthreads();
        int mycnt = (t < 256) ? hist[t] : 0;
        for (int off = 1; off < 256; off <<= 1) {
            int v = (t < 256 && t >= off) ? hist[t - off] : 0;
            __syncthreads();
            if (t < 256) hist[t] += v;
            __syncthreads();
        }
        if (t < 256) hist[t] -= mycnt;
        __syncthreads();
        for (int i = t; i < NN; i += 1024) {
            int b = 255 - min(((counts[i] + 3) & ~3) >> 2, 255);
            int pos = atomicAdd(&hist[b], 1);
            perm[pos] = i;
        }
    }
}

__global__ __launch_bounds__(1024) void k_build(
        const int* __restrict__ erow, const int* __restrict__ ecol,
        const float* __restrict__ attr, const float* __restrict__ dinv,
        const int* __restrict__ counts, const int* __restrict__ rowptr,
        int* cursor, int* csr_col, float* csr_nv) {
    int t = blockIdx.x * 1024 + threadIdx.x;
    if (t < NE) {
        int r = erow[t], c = ecol[t];
        int pos = atomicAdd(&cursor[r], 1);
        csr_col[pos] = c;
        csr_nv[pos] = dinv[r] * attr[t] * dinv[c];
    } else if (t - NE < NN) {
        int i = t - NE;
        int cnt = counts[i];
        int pcnt = (cnt + 3) & ~3;
        int base = rowptr[i + 1] - pcnt;
        for (int p = base + cnt; p < base + pcnt; ++p) { csr_col[p] = i; csr_nv[p] = 0.0f; }
    }
}

// ---------------- helpers ----------------
typedef float f4n __attribute__((ext_vector_type(4)));   // native vec for NT store
__device__ __forceinline__ void fma4(float4& a, float w, float4 v) {
    a.x = fmaf(w, v.x, a.x); a.y = fmaf(w, v.y, a.y);
    a.z = fmaf(w, v.z, a.z); a.w = fmaf(w, v.w, a.w);
}
__device__ __forceinline__ void fma2(float2& a, float w, float2 v) {
    a.x = fmaf(w, v.x, a.x); a.y = fmaf(w, v.y, a.y);
}
__device__ __forceinline__ float2 actv2(float2 v, float2 s, float2 t) {
    v.x = fmaxf(fmaf(v.x, s.x, t.x), 0.f);
    v.y = fmaxf(fmaf(v.y, s.y, t.y), 0.f);
    return v;
}
__device__ __forceinline__ void nt4(float4* p, float4 v) {
    f4n t; t.x = v.x; t.y = v.y; t.z = v.z; t.w = v.w;
    __builtin_nontemporal_store(t, (f4n*)p);
}

// ---------------- layer 0 (CIN=16, full batch): xt -> h1a/h1b ----------------
__global__ __launch_bounds__(256) void k_l16(
        const float* __restrict__ in,
        const float* __restrict__ W, const float* __restrict__ bias,
        const int* __restrict__ rowptr, const int* __restrict__ csr_col,
        const float* __restrict__ csr_nv, const float* __restrict__ dinv,
        const int* __restrict__ perm,
        float* __restrict__ outA, float* __restrict__ outB,
        float* __restrict__ stats) {
    const int ALS = 20;
    __shared__ float As[4 * 16 * ALS];
    int tid = threadIdx.x;
    int wid = tid >> 6, lane = tid & 63;
    int g = blockIdx.x & 7;
    int base = (blockIdx.x >> 3) * NPB + wid * 4;
    float* Aw = As + wid * 16 * ALS;
    const int4 pid = *(const int4*)(perm + base);

    const float* __restrict__ inr = in + (size_t)g * NN * 64;   // row = 64 floats
    int ids[4] = {pid.x, pid.y, pid.z, pid.w};
#pragma unroll
    for (int i = 0; i < 4; ++i) {
        int r = ids[i];
        float a = 0.f;
        if (r < NN) {
            float d = dinv[r];
            a = d * d * inr[(size_t)r * 64 + lane];
            int p0 = rowptr[r], p1 = rowptr[r + 1];
            for (int e = p0; e < p1; e += 4) {
                int4   cc = *(const int4*)(csr_col + e);
                float4 ww = *(const float4*)(csr_nv + e);
                float v0 = inr[(size_t)cc.x * 64 + lane];
                float v1 = inr[(size_t)cc.y * 64 + lane];
                float v2 = inr[(size_t)cc.z * 64 + lane];
                float v3 = inr[(size_t)cc.w * 64 + lane];
                a = fmaf(ww.x, v0, a);
                a = fmaf(ww.y, v1, a);
                a = fmaf(ww.z, v2, a);
                a = fmaf(ww.w, v3, a);
            }
        }
        Aw[(i * 4 + (lane >> 4)) * ALS + (lane & 15)] = a;
    }
    // NO barrier: stage 2 reads only this wave's Aw slice.

    int colq = lane & 15, rowq = lane >> 4;
    int node = (rowq == 0) ? pid.x : (rowq == 1) ? pid.y : (rowq == 2) ? pid.z : pid.w;

    const float4* __restrict__ W4 = (const float4*)W;
    float4 bb = ((const float4*)bias)[colq];
    float4 o[4];
#pragma unroll
    for (int i = 0; i < 4; ++i) o[i] = bb;
#pragma unroll
    for (int k = 0; k < 16; ++k) {
        float4 w4 = W4[k * 16 + colq];
#pragma unroll
        for (int i = 0; i < 4; ++i) {
            float a = Aw[(rowq * 4 + i) * ALS + k];
            fma4(o[i], a, w4);
        }
    }
    if (node < NN) {
        // half tensors: (g,n,2,64); cached stores (warm L2 for next layer's H0)
        float4* opA = (float4*)(outA + ((size_t)g * NN + node) * 128);
        float4* opB = (float4*)(outB + ((size_t)g * NN + node) * 128);
        opA[colq] = o[0]; opA[16 + colq] = o[1];
        opB[colq] = o[2]; opB[16 + colq] = o[3];
    }

    // stats (layer 0)
    float4 s4 = {0,0,0,0}, q4 = {0,0,0,0};
    if (node < NN) {
#pragma unroll
        for (int i = 0; i < 4; ++i) {
            s4.x += o[i].x; s4.y += o[i].y; s4.z += o[i].z; s4.w += o[i].w;
            q4.x = fmaf(o[i].x, o[i].x, q4.x); q4.y = fmaf(o[i].y, o[i].y, q4.y);
            q4.z = fmaf(o[i].z, o[i].z, q4.z); q4.w = fmaf(o[i].w, o[i].w, q4.w);
        }
    }
    s4.x += __shfl_xor(s4.x, 16); s4.y += __shfl_xor(s4.y, 16);
    s4.z += __shfl_xor(s4.z, 16); s4.w += __shfl_xor(s4.w, 16);
    q4.x += __shfl_xor(q4.x, 16); q4.y += __shfl_xor(q4.y, 16);
    q4.z += __shfl_xor(q4.z, 16); q4.w += __shfl_xor(q4.w, 16);
    s4.x += __shfl_xor(s4.x, 32); s4.y += __shfl_xor(s4.y, 32);
    s4.z += __shfl_xor(s4.z, 32); s4.w += __shfl_xor(s4.w, 32);
    q4.x += __shfl_xor(q4.x, 32); q4.y += __shfl_xor(q4.y, 32);
    q4.z += __shfl_xor(q4.z, 32); q4.w += __shfl_xor(q4.w, 32);
    __syncthreads();   // all waves done with As -> reuse as scratch
    if (lane < 16) {
        float* S = As + wid * 128;
        *(float4*)(S + lane * 8) = s4;
        *(float4*)(S + lane * 8 + 4) = q4;
    }
    __syncthreads();
    if (tid < 64) {
        int cq = tid >> 2, comp = tid & 3;
        float s = 0.f, q = 0.f;
#pragma unroll
        for (int w = 0; w < 4; ++w) {
            s += As[w * 128 + cq * 8 + comp];
            q += As[w * 128 + cq * 8 + 4 + comp];
        }
        float* sl = stats + (blockIdx.x & (NSLOT - 1)) * 128;
        atomicAdd(&sl[tid], s);
        atomicAdd(&sl[64 + tid], q);
    }
}

// ---------------- CIN=64 batch-half layer: in-half (g,n,2,64) -> out-half -----
// R27: 512B rows, 2.56MB/XCD footprint (L2-fit). Lane = (bi=lane>>5,
// c2=lane&31) loading float2; 8 gathers in flight via 2-node pair interleave.
// Inline BN+ReLU on gathered values. NT stores for out. SCORE=0: stage-2 GEMM
// o[2] + stats. SCORE=1: agg copy + score ch63 (global bi = half*2 + bi).
template<int SCORE>
__global__ __launch_bounds__(256) void k_l64(
        const float* __restrict__ in, const float* __restrict__ bnstats,
        const float* __restrict__ gamma, const float* __restrict__ beta,
        const float* __restrict__ W, const float* __restrict__ bias,
        const int* __restrict__ rowptr, const int* __restrict__ csr_col,
        const float* __restrict__ csr_nv, const float* __restrict__ dinv,
        const int* __restrict__ perm,
        float* __restrict__ out, float* __restrict__ stats,
        float* __restrict__ score, int half) {
    const int ALS = 68;
    __shared__ float As[4 * 8 * ALS];
    __shared__ float stl[128];
    int tid = threadIdx.x;
    int wid = tid >> 6, lane = tid & 63;
    int g = blockIdx.x & 7;
    int base = (blockIdx.x >> 3) * NPB + wid * 4;
    float* Aw = As + wid * 8 * ALS;
    const int4 pid = *(const int4*)(perm + base);

    if (tid < 64) {
        float su = 0.f, qu = 0.f;
#pragma unroll
        for (int s = 0; s < NSLOT; ++s) {
            su += bnstats[s * 128 + tid];
            qu += bnstats[s * 128 + 64 + tid];
        }
        const float inv = 1.0f / (float)(NB * NN);
        float mu = su * inv;
        float var = qu * inv - mu * mu;
        float sc = gamma[tid] / sqrtf(var + 1e-5f);
        stl[tid] = sc;
        stl[64 + tid] = fmaf(-mu, sc, beta[tid]);
    }
    __syncthreads();

    const float2* __restrict__ in2 = (const float2*)in + (size_t)g * NN * 64; // row = 64 f2
    float2 sv = ((const float2*)stl)[lane & 31];
    float2 tv = ((const float2*)(stl + 64))[lane & 31];
    int c2w = (lane & 31) << 1;   // As column (float index)
    int biw = lane >> 5;          // 0..1

#pragma unroll
    for (int pr = 0; pr < 2; ++pr) {
        int id0 = (pr == 0) ? pid.x : pid.z;
        int id1 = (pr == 0) ? pid.y : pid.w;
        bool vn0 = id0 < NN, vn1 = id1 < NN;
        int rc0 = vn0 ? id0 : 0, rc1 = vn1 ? id1 : 0;
        float dd0 = dinv[rc0]; dd0 *= dd0;
        float dd1 = dinv[rc1]; dd1 *= dd1;
        float2 a0 = {0.f, 0.f}, a1 = {0.f, 0.f};
        {
            float2 v0 = actv2(in2[(size_t)rc0 * 64 + lane], sv, tv);
            float2 v1 = actv2(in2[(size_t)rc1 * 64 + lane], sv, tv);
            if (vn0) { a0.x = dd0 * v0.x; a0.y = dd0 * v0.y; }
            if (vn1) { a1.x = dd1 * v1.x; a1.y = dd1 * v1.y; }
        }
        int p0a = rowptr[rc0], na = vn0 ? (rowptr[rc0 + 1] - p0a) >> 2 : 0;
        int p0b = rowptr[rc1], nbv = vn1 ? (rowptr[rc1 + 1] - p0b) >> 2 : 0;
        int mx = max(na, nbv);
        for (int bb = 0; bb < mx; ++bb) {
            int ea = min(p0a + 4 * bb, NEPAD - 4);
            int eb = min(p0b + 4 * bb, NEPAD - 4);
            bool va = bb < na, vb = bb < nbv;
            int4   ca = *(const int4*)(csr_col + ea);
            float4 wa = *(const float4*)(csr_nv + ea);
            int4   cb = *(const int4*)(csr_col + eb);
            float4 wb = *(const float4*)(csr_nv + eb);
            if (!va) { wa.x = 0.f; wa.y = 0.f; wa.z = 0.f; wa.w = 0.f;
                       ca.x = 0; ca.y = 0; ca.z = 0; ca.w = 0; }   // poisoned tail
            if (!vb) { wb.x = 0.f; wb.y = 0.f; wb.z = 0.f; wb.w = 0.f;
                       cb.x = 0; cb.y = 0; cb.z = 0; cb.w = 0; }
            float2 u0 = in2[(size_t)ca.x * 64 + lane];
            float2 u1 = in2[(size_t)ca.y * 64 + lane];
            float2 u2 = in2[(size_t)ca.z * 64 + lane];
            float2 u3 = in2[(size_t)ca.w * 64 + lane];
            float2 t0 = in2[(size_t)cb.x * 64 + lane];
            float2 t1 = in2[(size_t)cb.y * 64 + lane];
            float2 t2 = in2[(size_t)cb.z * 64 + lane];
            float2 t3 = in2[(size_t)cb.w * 64 + lane];
            fma2(a0, wa.x, actv2(u0, sv, tv));
            fma2(a0, wa.y, actv2(u1, sv, tv));
            fma2(a0, wa.z, actv2(u2, sv, tv));
            fma2(a0, wa.w, actv2(u3, sv, tv));
            fma2(a1, wb.x, actv2(t0, sv, tv));
            fma2(a1, wb.y, actv2(t1, sv, tv));
            fma2(a1, wb.z, actv2(t2, sv, tv));
            fma2(a1, wb.w, actv2(t3, sv, tv));
        }
        // As row = node*2 + bi (node = 2pr / 2pr+1)
        *(float2*)(Aw + (4 * pr + biw) * ALS + c2w) = a0;
        *(float2*)(Aw + (4 * pr + 2 + biw) * ALS + c2w) = a1;
    }
    // NO barrier: stage 2 reads only this wave's Aw slice.

    int colq = lane & 15, rowq = lane >> 4;
    int node = (rowq == 0) ? pid.x : (rowq == 1) ? pid.y : (rowq == 2) ? pid.z : pid.w;

    if (!SCORE) {
        const float4* __restrict__ W4 = (const float4*)W;
        float4 bb = ((const float4*)bias)[colq];
        float4 o0 = bb, o1 = bb;
#pragma unroll 8
        for (int k = 0; k < 64; ++k) {
            float4 w4 = W4[k * 16 + colq];
            fma4(o0, Aw[(rowq * 2 + 0) * ALS + k], w4);
            fma4(o1, Aw[(rowq * 2 + 1) * ALS + k], w4);
        }
        if (node < NN) {
            float4* __restrict__ op = (float4*)(out + ((size_t)g * NN + node) * 128);
            nt4(&op[colq], o0);
            nt4(&op[16 + colq], o1);
        }

        // stats (this half's contribution; adds commute across halves)
        float4 s4 = {0,0,0,0}, q4 = {0,0,0,0};
        if (node < NN) {
            s4.x = o0.x + o1.x; s4.y = o0.y + o1.y; s4.z = o0.z + o1.z; s4.w = o0.w + o1.w;
            q4.x = fmaf(o0.x, o0.x, o1.x * o1.x); q4.y = fmaf(o0.y, o0.y, o1.y * o1.y);
            q4.z = fmaf(o0.z, o0.z, o1.z * o1.z); q4.w = fmaf(o0.w, o0.w, o1.w * o1.w);
        }
        s4.x += __shfl_xor(s4.x, 16); s4.y += __shfl_xor(s4.y, 16);
        s4.z += __shfl_xor(s4.z, 16); s4.w += __shfl_xor(s4.w, 16);
        q4.x += __shfl_xor(q4.x, 16); q4.y += __shfl_xor(q4.y, 16);
        q4.z += __shfl_xor(q4.z, 16); q4.w += __shfl_xor(q4.w, 16);
        s4.x += __shfl_xor(s4.x, 32); s4.y += __shfl_xor(s4.y, 32);
        s4.z += __shfl_xor(s4.z, 32); s4.w += __shfl_xor(s4.w, 32);
        q4.x += __shfl_xor(q4.x, 32); q4.y += __shfl_xor(q4.y, 32);
        q4.z += __shfl_xor(q4.z, 32); q4.w += __shfl_xor(q4.w, 32);
        __syncthreads();   // all waves done with As -> reuse as scratch
        if (lane < 16) {
            float* S = As + wid * 128;
            *(float4*)(S + lane * 8) = s4;
            *(float4*)(S + lane * 8 + 4) = q4;
        }
        __syncthreads();
        if (tid < 64) {
            int cq = tid >> 2, comp = tid & 3;
            float s = 0.f, q = 0.f;
#pragma unroll
            for (int w = 0; w < 4; ++w) {
                s += As[w * 128 + cq * 8 + comp];
                q += As[w * 128 + cq * 8 + 4 + comp];
            }
            float* sl = stats + (blockIdx.x & (NSLOT - 1)) * 128;
            atomicAdd(&sl[tid], s);
            atomicAdd(&sl[64 + tid], q);
        }
    } else {
        // agg copy from LDS (half layout) + compact relu'd score (ch 63)
        if (node < NN) {
            float4* __restrict__ op = (float4*)(out + ((size_t)g * NN + node) * 128);
            nt4(&op[colq],      *(const float4*)(Aw + (rowq * 2 + 0) * ALS + colq * 4));
            nt4(&op[16 + colq], *(const float4*)(Aw + (rowq * 2 + 1) * ALS + colq * 4));
        }
        if (lane < 8) {
            int q = lane >> 1;
            int nd = (q == 0) ? pid.x : (q == 1) ? pid.y : (q == 2) ? pid.z : pid.w;
            if (nd < NN) {
                float s = bias[63];
                const float* Ar = Aw + lane * ALS;   // row lane = (node lane>>1, bi lane&1)
#pragma unroll 8
                for (int k = 0; k < 64; ++k)
                    s = fmaf(Ar[k], W[k * 64 + 63], s);
                score[((size_t)g * NN + nd) * 4 + half * 2 + (lane & 1)] = fmaxf(s, 0.f);
            }
        }
    }
}

// ---------------- sort-pool (blocks 0..31) + bnfin (block 32) ----------------
__global__ __launch_bounds__(1024) void k_toppool(const float* __restrict__ sc, int* order,
        const float* __restrict__ stats,
        const float* __restrict__ g0, const float* __restrict__ be0,
        const float* __restrict__ g1, const float* __restrict__ be1,
        float* __restrict__ st) {
    __shared__ unsigned long long wbest[16];
    __shared__ unsigned long long winner;
    int tid = threadIdx.x;
    if (blockIdx.x == NB) {
        if (tid < 128) {
            int c = tid & 63, layer = tid >> 6;
            const float* sb = stats + layer * NSLOT * 128;
            float su = 0.f, qu = 0.f;
#pragma unroll
            for (int s = 0; s < NSLOT; ++s) {
                su += sb[s * 128 + c];
                qu += sb[s * 128 + 64 + c];
            }
            const float inv = 1.0f / (float)(NB * NN);
            float mu = su * inv;
            float var = qu * inv - mu * mu;
            float g = layer ? g1[c] : g0[c];
            float be = layer ? be1[c] : be0[c];
            float scv = g / sqrtf(var + 1e-5f);
            st[layer * 128 + c] = scv;
            st[layer * 128 + 64 + c] = fmaf(-mu, scv, be);
        }
        return;
    }
    int b = blockIdx.x;
    int g = b >> 2, bi = b & 3;
    int lane = tid & 63, wid = tid >> 6;
    unsigned long long key[5];
#pragma unroll
    for (int j = 0; j < 5; ++j) {
        int n = tid + j * 1024;
        unsigned long long k = 0;
        if (n < NN) {
            float v = sc[((size_t)g * NN + n) * GB + bi];   // already relu'd
            k = ((unsigned long long)__float_as_uint(v) << 32) | (unsigned int)(NN - n);
        }
        key[j] = k;
    }
    for (int k = 0; k < KPOOL; ++k) {
        unsigned long long best = key[0];
#pragma unroll
        for (int j = 1; j < 5; ++j) best = (key[j] > best) ? key[j] : best;
#pragma unroll
        for (int off = 1; off < 64; off <<= 1) {
            unsigned long long o = __shfl_xor(best, off);
            best = (o > best) ? o : best;
        }
        if (lane == 0) wbest[wid] = best;
        __syncthreads();
        if (tid == 0) {
            unsigned long long w = wbest[0];
#pragma unroll
            for (int i = 1; i < 16; ++i) w = (wbest[i] > w) ? wbest[i] : w;
            winner = w;
            order[b * KPOOL + k] = NN - (int)(w & 0xFFFFFFFFu);
        }
        __syncthreads();
        int n = NN - (int)(winner & 0xFFFFFFFFu);
        if ((n & 1023) == tid) key[n >> 10] = 0;   // remove winner (owner thread)
    }
}

// ---------------- gather selected nodes into flat (B, 6241) ----------------
__global__ void k_gather(const float* __restrict__ xt,
                         const float* __restrict__ h1a, const float* __restrict__ h1b,
                         const float* __restrict__ h2a, const float* __restrict__ h2b,
                         const float* __restrict__ aggA, const float* __restrict__ aggB,
                         const float* __restrict__ W2, const float* __restrict__ b2,
                         const float* __restrict__ st, const float* __restrict__ age,
                         const int* __restrict__ order, float* __restrict__ flat) {
    int bk = blockIdx.x;
    int b = bk / KPOOL, k = bk % KPOOL;
    int n = order[bk];
    int g = b >> 2, bi = b & 3;
    size_t hoff = ((size_t)g * NN + n) * 2 + (bi & 1);   // half-tensor row
    int f = threadIdx.x;
    float val = 0.f;
    if (f < DIN) {
        val = xt[(((size_t)g * NN + n) * GB + bi) * DIN + f];
    } else if (f < DIN + CH) {
        int c = f - DIN;
        const float* h = (bi < 2) ? h1a : h1b;
        val = fmaxf(fmaf(h[hoff * 64 + c], st[c], st[64 + c]), 0.f);
    } else if (f < DIN + 2 * CH) {
        int c = f - DIN - CH;
        const float* h = (bi < 2) ? h2a : h2b;
        val = fmaxf(fmaf(h[hoff * 64 + c], st[128 + c], st[192 + c]), 0.f);
    } else if (f < FTOT) {
        int c = f - DIN - 2 * CH;
        const float* __restrict__ Ar = ((bi < 2) ? aggA : aggB) + hoff * 64;
        float s = b2[c];
#pragma unroll 8
        for (int kk = 0; kk < 64; ++kk)
            s = fmaf(Ar[kk], W2[kk * 64 + c], s);   // Ar broadcast, W2 coalesced
        val = fmaxf(s, 0.f);
    }
    if (f < FTOT) flat[(size_t)b * FLATW + k * FTOT + f] = val;
    if (bk == 0 && f >= FTOT && f < FTOT + NB)
        flat[(size_t)(f - FTOT) * FLATW + (FLATW - 1)] = age[f - FTOT];
}

// ---------------- MLP head layer 1: hm += flat @ mW0 (k-split, atomics) ----------------
__global__ void k_head1(const float* __restrict__ flat, const float* __restrict__ mW0,
                        float* hm) {
    int tid = threadIdx.x;
    int j4 = (tid & 31) * 4;       // 32 groups * 4 = 128 cols
    int b0 = (tid >> 5) * 4;       // 8 groups * 4 = 32 rows
    int kbase = blockIdx.x * 64;
    float acc[4][4];
#pragma unroll
    for (int i = 0; i < 4; i++)
#pragma unroll
        for (int jj = 0; jj < 4; jj++) acc[i][jj] = 0.f;
    int kend = FLATW - kbase; if (kend > 64) kend = 64;
    for (int kk = 0; kk < kend; ++kk) {
        int k = kbase + kk;
        float4 w = *(const float4*)(mW0 + (size_t)k * NH + j4);
#pragma unroll
        for (int i = 0; i < 4; i++) {
            float fv = flat[(size_t)(b0 + i) * FLATW + k];
            acc[i][0] = fmaf(fv, w.x, acc[i][0]);
            acc[i][1] = fmaf(fv, w.y, acc[i][1]);
            acc[i][2] = fmaf(fv, w.z, acc[i][2]);
            acc[i][3] = fmaf(fv, w.w, acc[i][3]);
        }
    }
#pragma unroll
    for (int i = 0; i < 4; i++)
#pragma unroll
        for (int jj = 0; jj < 4; jj++)
            atomicAdd(&hm[(size_t)(b0 + i) * NH + j4 + jj], acc[i][jj]);
}

// ---------------- head layer 2 + log_softmax (4-way j-split) ----------------
__global__ void k_head2(const float* __restrict__ hm, const float* __restrict__ mb0,
                        const float* __restrict__ mW1, const float* __restrict__ mb1,
                        float* __restrict__ out) {
    __shared__ float part[256];
    __shared__ float vals[64];
    int tid = threadIdx.x;  // 256 = 32b * 2o * 4q
    int q = tid & 3, o = (tid >> 2) & 1, b = tid >> 3;
    float acc = 0.f;
    for (int j = q * 32; j < q * 32 + 32; ++j) {
        float hv = fmaxf(hm[b * NH + j] + mb0[j], 0.f);
        acc = fmaf(hv, mW1[j * 2 + o], acc);
    }
    part[tid] = acc;
    __syncthreads();
    if (tid < 64) {
        int b2 = tid >> 1, o2 = tid & 1;
        int base = (b2 << 3) + (o2 << 2);
        vals[tid] = part[base] + part[base + 1] + part[base + 2] + part[base + 3] + mb1[o2];
    }
    __syncthreads();
    if (tid < 64) {
        int b2 = tid >> 1;
        float v0 = vals[b2 * 2], v1 = vals[b2 * 2 + 1];
        float m = fmaxf(v0, v1);
        float lse = m + logf(expf(v0 - m) + expf(v1 - m));
        out[tid] = vals[tid] - lse;
    }
}

extern "C" void kernel_launch(void* const* d_in, const int* in_sizes, int n_in,
                              void* d_out, int out_size, void* d_ws, size_t ws_size,
                              hipStream_t stream) {
    const float* x    = (const float*)d_in[0];
    const float* age  = (const float*)d_in[1];
    const float* attr = (const float*)d_in[2];
    const float* W0   = (const float*)d_in[3];
    const float* b0   = (const float*)d_in[4];
    const float* W1   = (const float*)d_in[5];
    const float* b1   = (const float*)d_in[6];
    const float* W2   = (const float*)d_in[7];
    const float* b2   = (const float*)d_in[8];
    const float* g0   = (const float*)d_in[9];
    const float* be0  = (const float*)d_in[10];
    const float* g1   = (const float*)d_in[11];
    const float* be1  = (const float*)d_in[12];
    const float* mW0  = (const float*)d_in[13];
    const float* mb0  = (const float*)d_in[14];
    const float* mW1  = (const float*)d_in[15];
    const float* mb1  = (const float*)d_in[16];
    const int* erow   = (const int*)d_in[17];
    const int* ecol   = (const int*)d_in[18];
    float* out = (float*)d_out;

    // workspace layout (floats); all float4-aligned
    float* ws     = (float*)d_ws;
    float* deg    = ws;                                  // 5008
    float* dinv   = deg + 5008;                          // 5008
    int*   counts = (int*)(dinv + 5008);                 // 5008
    int*   rowptr = counts + 5008;                       // 5008
    int*   cursor = rowptr + 5008;                       // 5008
    int*   perm   = cursor + 5008;                       // 5008
    int*   csr_col= perm + 5008;                         // NEPAD
    float* csr_nv = (float*)(csr_col + NEPAD);           // NEPAD
    float* stats  = csr_nv + NEPAD;                      // 2*32*128 = 8192
    float* st     = stats + 2 * NSLOT * 128;             // 256 (s0,t0,s1,t1)
    float* sc     = st + 256;                            // NB*NN = 160000 (scores)
    int*   order  = (int*)(sc + NB * NN);                // 960
    float* flat   = (float*)(order + 960);               // 32*6241
    float* hm     = flat + (size_t)NB * FLATW;           // 4096
    float* xt     = hm + 4096;                           // (G8,N,4,16)
    const size_t HT = (size_t)NG * NN * 2 * CH;          // half-tensor = 5.12M floats
    float* h1a    = xt + (size_t)NB * NN * DIN;
    float* h1b    = h1a + HT;
    float* h2a    = h1b + HT;
    float* h2b    = h2a + HT;
    float* aggA   = h2b + HT;
    float* aggB   = aggA + HT;

    // graph build: scan+sort+transpose share one dispatch (concurrent roles)
    k_init<<<32, 256, 0, stream>>>(deg, counts, stats, hm, perm);
    k_edges<<<NEB, 256, 0, stream>>>(attr, erow, deg, counts);
    k_phase1<<<2 + (NB * NN + 1023) / 1024, 1024, 0, stream>>>(counts, deg, rowptr, cursor, dinv, perm, x, xt);
    k_build<<<(NE + NN + 1023) / 1024, 1024, 0, stream>>>(erow, ecol, attr, dinv, counts, rowptr, cursor, csr_col, csr_nv);

    const int NBLK = NCHUNK * NG;   // 313 * 8
    // layer 0 (full batch) then batch-half CIN64 layers (L2-fit footprint)
    k_l16<<<NBLK, 256, 0, stream>>>(xt, W0, b0, rowptr, csr_col, csr_nv, dinv, perm, h1a, h1b, stats);
    k_l64<0><<<NBLK, 256, 0, stream>>>(h1a, stats, g0, be0, W1, b1, rowptr, csr_col, csr_nv, dinv, perm, h2a, stats + NSLOT * 128, nullptr, 0);
    k_l64<0><<<NBLK, 256, 0, stream>>>(h1b, stats, g0, be0, W1, b1, rowptr, csr_col, csr_nv, dinv, perm, h2b, stats + NSLOT * 128, nullptr, 1);
    k_l64<1><<<NBLK, 256, 0, stream>>>(h2a, stats + NSLOT * 128, g1, be1, W2, b2, rowptr, csr_col, csr_nv, dinv, perm, aggA, nullptr, sc, 0);
    k_l64<1><<<NBLK, 256, 0, stream>>>(h2b, stats + NSLOT * 128, g1, be1, W2, b2, rowptr, csr_col, csr_nv, dinv, perm, aggB, nullptr, sc, 1);

    // sort-pool (+fused bnfin) + gather (deferred GEMM) + head
    k_toppool<<<NB + 1, 1024, 0, stream>>>(sc, order, stats, g0, be0, g1, be1, st);
    k_gather<<<NB * KPOOL, 256, 0, stream>>>(xt, h1a, h1b, h2a, h2b, aggA, aggB, W2, b2, st, age, order, flat);
    k_head1<<<(FLATW + 63) / 64, 256, 0, stream>>>(flat, mW0, hm);
    k_head2<<<1, 256, 0, stream>>>(hm, mb0, mW1, mb1, out);
}

// Round 9
// 392.630 us; speedup vs baseline: 1.0793x; 1.0793x over previous
//
#include <hip/hip_runtime.h>
#include <math.h>

// Problem constants (from reference setup_inputs)
#define NN    5000      // nodes
#define NE    80000     // edges
#define NB    32        // batch
#define DIN   16        // input feat
#define CH    64        // conv channels
#define KPOOL 30
#define FTOT  208      // 16 + 3*64
#define FLATW 6241     // KPOOL*FTOT + 1
#define NH    128      // MLP hidden
#define NG    8        // batch groups for layer-0 input layout
#define GB    4        // batches per group (layer-0 input)
#define NPB   16       // nodes per block (4 per wave)
#define NCHUNK 313     // node chunks
#define NPAD  5008     // perm array size
#define NEPAD (NE + 4 * NN)   // CSR rows padded to multiple of 4
#define NSLOT 32       // stats atomic-spread slots

// Journal: R19 ordering / R20+R24 occupancy: dead. R21 CSR rotate: neutral.
// R22 act-hoist: -43% VALU -> -5% dur. R26 serial-merge: 354->348.6.
// R27/28 batch-half split: FETCH 114->13MB (perfect L2 fit) yet per-pass only
// -13% at SAME iteration count; passes doubled -> 423us. COST MODEL PROVEN:
// time per pass ~ # dependent gather ITERATIONS; bytes/miss-rate/VALU nearly
// free. R29 (this): go WIDER, not narrower. CIN64 layers use G=4 groups of 8
// batches (2KB rows, 2xfloat4/lane/edge): iterations per pass HALVED at
// constant instruction count. Group g on XCDs {g,g+4} via blockIdx&3. Layer-0
// keeps G8 read, writes G4 layout. Win pred: k_l64 ~40-48us. Null (~70us) =>
// instruction-rate floor => fp32 layers done, pivot to tail.
// Spill canary: k_l64 WRITE_SIZE must stay ~41-45MB.

// ---------------- setup kernels ----------------

__global__ void k_init(float* deg, int* counts, float* stats, float* hm, int* perm) {
    int i = blockIdx.x * 256 + threadIdx.x;
    if (i < NN) { deg[i] = 1.0f; counts[i] = 0; }   // deg starts at self-loop value 1
    if (i < 2 * NSLOT * 128) stats[i] = 0.0f;       // [2 layers][32 slots][128]
    if (i < 4096) hm[i] = 0.0f;
    if (i >= NN && i < NPAD) perm[i] = NN;          // tail -> invalid marker
}

#define NEB 313
__global__ void k_edges(const float* __restrict__ attr, const int* __restrict__ erow,
                        float* deg, int* counts) {
    int e = blockIdx.x * 256 + threadIdx.x;
    if (e < NE) {
        int r = erow[e];
        atomicAdd(&deg[r], attr[e]);
        atomicAdd(&counts[r], 1);
    }
}

// merged concurrent phase: block 0 = prefix scan, block 1 = counting sort,
// blocks 2.. = x transpose (serial roles hide under the wide transpose).
__global__ __launch_bounds__(1024) void k_phase1(
        const int* __restrict__ counts, const float* __restrict__ deg,
        int* rowptr, int* cursor, float* dinv, int* perm,
        const float* __restrict__ x, float* __restrict__ xt) {
    __shared__ int wsum[16], woff[16];
    __shared__ int carry_sh;
    __shared__ int hist[256];
    int t = threadIdx.x;
    if (blockIdx.x >= 2) {
        int idx = (blockIdx.x - 2) * 1024 + t;
        if (idx >= NB * NN) return;
        int b = idx / NN, n = idx % NN;
        int g = b >> 2, bi = b & 3;
        const float4* src = (const float4*)(x + (size_t)idx * DIN);
        float4* dst = (float4*)(xt + (((size_t)g * NN + n) * GB + bi) * DIN);
        dst[0] = src[0]; dst[1] = src[1]; dst[2] = src[2]; dst[3] = src[3];
        return;
    }
    if (blockIdx.x == 0) {
        int lane = t & 63, wid = t >> 6;
        if (t == 0) carry_sh = 0;
        __syncthreads();
        for (int base = 0; base < NN; base += 1024) {
            int carry = carry_sh;
            int i = base + t;
            int v = 0;
            if (i < NN) {
                v = (counts[i] + 3) & ~3;
                dinv[i] = 1.0f / sqrtf(deg[i]);   // deg >= 1 always
            }
            int s = v;
#pragma unroll
            for (int off = 1; off < 64; off <<= 1) {
                int o = __shfl_up(s, off);
                if (lane >= off) s += o;
            }
            if (lane == 63) wsum[wid] = s;
            __syncthreads();
            if (t < 16) {
                int w = wsum[t];
#pragma unroll
                for (int off = 1; off < 16; off <<= 1) {
                    int o = __shfl_up(w, off);
                    if (t >= off) w += o;
                }
                woff[t] = w;
            }
            __syncthreads();
            int inc = s + (wid > 0 ? woff[wid - 1] : 0) + carry;
            if (i < NN) {
                rowptr[i + 1] = inc;
                cursor[i] = inc - v;
            }
            if (t == 1023) carry_sh = carry + woff[15];
            __syncthreads();
        }
        if (t == 0) rowptr[0] = 0;
    } else {
        if (t < 256) hist[t] = 0;
        __syncthreads();
        for (int i = t; i < NN; i += 1024) {
            int b = 255 - min(((counts[i] + 3) & ~3) >> 2, 255);
            atomicAdd(&hist[b], 1);
        }
        __syncthreads();
        int mycnt = (t < 256) ? hist[t] : 0;
        for (int off = 1; off < 256; off <<= 1) {
            int v = (t < 256 && t >= off) ? hist[t - off] : 0;
            __syncthreads();
            if (t < 256) hist[t] += v;
            __syncthreads();
        }
        if (t < 256) hist[t] -= mycnt;
        __syncthreads();
        for (int i = t; i < NN; i += 1024) {
            int b = 255 - min(((counts[i] + 3) & ~3) >> 2, 255);
            int pos = atomicAdd(&hist[b], 1);
            perm[pos] = i;
        }
    }
}

__global__ __launch_bounds__(1024) void k_build(
        const int* __restrict__ erow, const int* __restrict__ ecol,
        const float* __restrict__ attr, const float* __restrict__ dinv,
        const int* __restrict__ counts, const int* __restrict__ rowptr,
        int* cursor, int* csr_col, float* csr_nv) {
    int t = blockIdx.x * 1024 + threadIdx.x;
    if (t < NE) {
        int r = erow[t], c = ecol[t];
        int pos = atomicAdd(&cursor[r], 1);
        csr_col[pos] = c;
        csr_nv[pos] = dinv[r] * attr[t] * dinv[c];
    } else if (t - NE < NN) {
        int i = t - NE;
        int cnt = counts[i];
        int pcnt = (cnt + 3) & ~3;
        int base = rowptr[i + 1] - pcnt;
        for (int p = base + cnt; p < base + pcnt; ++p) { csr_col[p] = i; csr_nv[p] = 0.0f; }
    }
}

// ---------------- helpers ----------------
typedef float f4n __attribute__((ext_vector_type(4)));   // native vec for NT store
__device__ __forceinline__ void fma4(float4& a, float w, float4 v) {
    a.x = fmaf(w, v.x, a.x); a.y = fmaf(w, v.y, a.y);
    a.z = fmaf(w, v.z, a.z); a.w = fmaf(w, v.w, a.w);
}
__device__ __forceinline__ float4 actv(float4 v, float4 s, float4 t) {
    v.x = fmaxf(fmaf(v.x, s.x, t.x), 0.f);
    v.y = fmaxf(fmaf(v.y, s.y, t.y), 0.f);
    v.z = fmaxf(fmaf(v.z, s.z, t.z), 0.f);
    v.w = fmaxf(fmaf(v.w, s.w, t.w), 0.f);
    return v;
}
__device__ __forceinline__ void nt4(float4* p, float4 v) {
    f4n t; t.x = v.x; t.y = v.y; t.z = v.z; t.w = v.w;
    __builtin_nontemporal_store(t, (f4n*)p);
}

// ---------------- layer 0 (CIN=16): xt (G8,N,4,16) -> h1 (G4,N,8,64) --------
__global__ __launch_bounds__(256) void k_l16(
        const float* __restrict__ in,
        const float* __restrict__ W, const float* __restrict__ bias,
        const int* __restrict__ rowptr, const int* __restrict__ csr_col,
        const float* __restrict__ csr_nv, const float* __restrict__ dinv,
        const int* __restrict__ perm,
        float* __restrict__ out, float* __restrict__ stats) {
    const int ALS = 20;
    __shared__ float As[4 * 16 * ALS];
    int tid = threadIdx.x;
    int wid = tid >> 6, lane = tid & 63;
    int g = blockIdx.x & 7;
    int base = (blockIdx.x >> 3) * NPB + wid * 4;
    float* Aw = As + wid * 16 * ALS;
    const int4 pid = *(const int4*)(perm + base);

    const float* __restrict__ inr = in + (size_t)g * NN * 64;   // row = 64 floats
    int ids[4] = {pid.x, pid.y, pid.z, pid.w};
#pragma unroll
    for (int i = 0; i < 4; ++i) {
        int r = ids[i];
        float a = 0.f;
        if (r < NN) {
            float d = dinv[r];
            a = d * d * inr[(size_t)r * 64 + lane];
            int p0 = rowptr[r], p1 = rowptr[r + 1];
            for (int e = p0; e < p1; e += 4) {
                int4   cc = *(const int4*)(csr_col + e);
                float4 ww = *(const float4*)(csr_nv + e);
                float v0 = inr[(size_t)cc.x * 64 + lane];
                float v1 = inr[(size_t)cc.y * 64 + lane];
                float v2 = inr[(size_t)cc.z * 64 + lane];
                float v3 = inr[(size_t)cc.w * 64 + lane];
                a = fmaf(ww.x, v0, a);
                a = fmaf(ww.y, v1, a);
                a = fmaf(ww.z, v2, a);
                a = fmaf(ww.w, v3, a);
            }
        }
        Aw[(i * 4 + (lane >> 4)) * ALS + (lane & 15)] = a;
    }
    // NO barrier: stage 2 reads only this wave's Aw slice.

    int colq = lane & 15, rowq = lane >> 4;
    int node = (rowq == 0) ? pid.x : (rowq == 1) ? pid.y : (rowq == 2) ? pid.z : pid.w;

    const float4* __restrict__ W4 = (const float4*)W;
    float4 bb = ((const float4*)bias)[colq];
    float4 o[4];
#pragma unroll
    for (int i = 0; i < 4; ++i) o[i] = bb;
#pragma unroll
    for (int k = 0; k < 16; ++k) {
        float4 w4 = W4[k * 16 + colq];
#pragma unroll
        for (int i = 0; i < 4; ++i) {
            float a = Aw[(rowq * 4 + i) * ALS + k];
            fma4(o[i], a, w4);
        }
    }
    if (node < NN) {
        // G4 layout: batch b = g*4+i -> (g4 = g>>1, bi8 = (g&1)*4 + i)
        float4* op = (float4*)(out + (((size_t)(g >> 1) * NN + node) * 8 + (g & 1) * 4) * 64);
#pragma unroll
        for (int i = 0; i < 4; ++i) op[i * 16 + colq] = o[i];
    }

    // stats (layer 0)
    float4 s4 = {0,0,0,0}, q4 = {0,0,0,0};
    if (node < NN) {
#pragma unroll
        for (int i = 0; i < 4; ++i) {
            s4.x += o[i].x; s4.y += o[i].y; s4.z += o[i].z; s4.w += o[i].w;
            q4.x = fmaf(o[i].x, o[i].x, q4.x); q4.y = fmaf(o[i].y, o[i].y, q4.y);
            q4.z = fmaf(o[i].z, o[i].z, q4.z); q4.w = fmaf(o[i].w, o[i].w, q4.w);
        }
    }
    s4.x += __shfl_xor(s4.x, 16); s4.y += __shfl_xor(s4.y, 16);
    s4.z += __shfl_xor(s4.z, 16); s4.w += __shfl_xor(s4.w, 16);
    q4.x += __shfl_xor(q4.x, 16); q4.y += __shfl_xor(q4.y, 16);
    q4.z += __shfl_xor(q4.z, 16); q4.w += __shfl_xor(q4.w, 16);
    s4.x += __shfl_xor(s4.x, 32); s4.y += __shfl_xor(s4.y, 32);
    s4.z += __shfl_xor(s4.z, 32); s4.w += __shfl_xor(s4.w, 32);
    q4.x += __shfl_xor(q4.x, 32); q4.y += __shfl_xor(q4.y, 32);
    q4.z += __shfl_xor(q4.z, 32); q4.w += __shfl_xor(q4.w, 32);
    __syncthreads();   // all waves done with As -> reuse as scratch
    if (lane < 16) {
        float* S = As + wid * 128;
        *(float4*)(S + lane * 8) = s4;
        *(float4*)(S + lane * 8 + 4) = q4;
    }
    __syncthreads();
    if (tid < 64) {
        int cq = tid >> 2, comp = tid & 3;
        float s = 0.f, q = 0.f;
#pragma unroll
        for (int w = 0; w < 4; ++w) {
            s += As[w * 128 + cq * 8 + comp];
            q += As[w * 128 + cq * 8 + 4 + comp];
        }
        float* sl = stats + (blockIdx.x & (NSLOT - 1)) * 128;
        atomicAdd(&sl[tid], s);
        atomicAdd(&sl[64 + tid], q);
    }
}

// ---------------- CIN=64 G4 layer: in (G4,N,8,64) -> out (G4,N,8,64) ---------
// R29: 2KB rows; lane covers (bi8 = lane>>3, ch0 = (lane&7)*8) = 2 float4 per
// edge-gather. Iterations per pass HALVED (4 groups x 25K bundles). Pair-
// interleave 2 nodes -> 16 gathers in flight. Inline BN+ReLU. NT out stores.
// Group g -> XCDs {g, g+4} via blockIdx&3. Grid 313*4 = 1252 blocks.
template<int SCORE>
__global__ __launch_bounds__(256) void k_l64(
        const float* __restrict__ in, const float* __restrict__ bnstats,
        const float* __restrict__ gamma, const float* __restrict__ beta,
        const float* __restrict__ W, const float* __restrict__ bias,
        const int* __restrict__ rowptr, const int* __restrict__ csr_col,
        const float* __restrict__ csr_nv, const float* __restrict__ dinv,
        const int* __restrict__ perm,
        float* __restrict__ out, float* __restrict__ stats,
        float* __restrict__ score) {
    const int ALS = 68;
    __shared__ float As[4 * 32 * ALS];   // 4 waves x (4 nodes x 8 bi) x 68 = 34816B
    __shared__ float stl[128];
    int tid = threadIdx.x;
    int wid = tid >> 6, lane = tid & 63;
    int g = blockIdx.x & 3;                       // group of 8 batches
    int base = (blockIdx.x >> 2) * NPB + wid * 4;
    float* Aw = As + wid * 32 * ALS;
    const int4 pid = *(const int4*)(perm + base);

    if (tid < 64) {
        float su = 0.f, qu = 0.f;
#pragma unroll
        for (int s = 0; s < NSLOT; ++s) {
            su += bnstats[s * 128 + tid];
            qu += bnstats[s * 128 + 64 + tid];
        }
        const float inv = 1.0f / (float)(NB * NN);
        float mu = su * inv;
        float var = qu * inv - mu * mu;
        float sc = gamma[tid] / sqrtf(var + 1e-5f);
        stl[tid] = sc;
        stl[64 + tid] = fmaf(-mu, sc, beta[tid]);
    }
    __syncthreads();

    const float4* __restrict__ in4 = (const float4*)in + (size_t)g * NN * 128; // row = 128 f4
    int chq = (lane & 7) * 2;   // float4 index of this lane's 8-ch slice
    float4 sv0 = ((const float4*)stl)[chq],      sv1 = ((const float4*)stl)[chq + 1];
    float4 tv0 = ((const float4*)(stl + 64))[chq], tv1 = ((const float4*)(stl + 64))[chq + 1];
    int bi8 = lane >> 3;
    int ch0 = (lane & 7) * 8;

#pragma unroll
    for (int pr = 0; pr < 2; ++pr) {
        int id0 = (pr == 0) ? pid.x : pid.z;
        int id1 = (pr == 0) ? pid.y : pid.w;
        bool vn0 = id0 < NN, vn1 = id1 < NN;
        int rc0 = vn0 ? id0 : 0, rc1 = vn1 ? id1 : 0;
        float dd0 = dinv[rc0]; dd0 *= dd0;
        float dd1 = dinv[rc1]; dd1 *= dd1;
        float4 a00 = {0,0,0,0}, a01 = {0,0,0,0};
        float4 a10 = {0,0,0,0}, a11 = {0,0,0,0};
        {
            float4 v00 = actv(in4[(size_t)rc0 * 128 + 2 * lane],     sv0, tv0);
            float4 v01 = actv(in4[(size_t)rc0 * 128 + 2 * lane + 1], sv1, tv1);
            float4 v10 = actv(in4[(size_t)rc1 * 128 + 2 * lane],     sv0, tv0);
            float4 v11 = actv(in4[(size_t)rc1 * 128 + 2 * lane + 1], sv1, tv1);
            if (vn0) { fma4(a00, dd0, v00); fma4(a01, dd0, v01); }
            if (vn1) { fma4(a10, dd1, v10); fma4(a11, dd1, v11); }
        }
        int p0a = rowptr[rc0], na = vn0 ? (rowptr[rc0 + 1] - p0a) >> 2 : 0;
        int p0b = rowptr[rc1], nbv = vn1 ? (rowptr[rc1 + 1] - p0b) >> 2 : 0;
        int mx = max(na, nbv);
        for (int bb = 0; bb < mx; ++bb) {
            int ea = min(p0a + 4 * bb, NEPAD - 4);
            int eb = min(p0b + 4 * bb, NEPAD - 4);
            bool va = bb < na, vb = bb < nbv;
            int4   ca = *(const int4*)(csr_col + ea);
            float4 wa = *(const float4*)(csr_nv + ea);
            int4   cb = *(const int4*)(csr_col + eb);
            float4 wb = *(const float4*)(csr_nv + eb);
            if (!va) { wa.x = 0.f; wa.y = 0.f; wa.z = 0.f; wa.w = 0.f;
                       ca.x = 0; ca.y = 0; ca.z = 0; ca.w = 0; }   // poisoned tail
            if (!vb) { wb.x = 0.f; wb.y = 0.f; wb.z = 0.f; wb.w = 0.f;
                       cb.x = 0; cb.y = 0; cb.z = 0; cb.w = 0; }
            float4 u00 = in4[(size_t)ca.x * 128 + 2 * lane], u01 = in4[(size_t)ca.x * 128 + 2 * lane + 1];
            float4 u10 = in4[(size_t)ca.y * 128 + 2 * lane], u11 = in4[(size_t)ca.y * 128 + 2 * lane + 1];
            float4 u20 = in4[(size_t)ca.z * 128 + 2 * lane], u21 = in4[(size_t)ca.z * 128 + 2 * lane + 1];
            float4 u30 = in4[(size_t)ca.w * 128 + 2 * lane], u31 = in4[(size_t)ca.w * 128 + 2 * lane + 1];
            float4 t00 = in4[(size_t)cb.x * 128 + 2 * lane], t01 = in4[(size_t)cb.x * 128 + 2 * lane + 1];
            float4 t10 = in4[(size_t)cb.y * 128 + 2 * lane], t11 = in4[(size_t)cb.y * 128 + 2 * lane + 1];
            float4 t20 = in4[(size_t)cb.z * 128 + 2 * lane], t21 = in4[(size_t)cb.z * 128 + 2 * lane + 1];
            float4 t30 = in4[(size_t)cb.w * 128 + 2 * lane], t31 = in4[(size_t)cb.w * 128 + 2 * lane + 1];
            fma4(a00, wa.x, actv(u00, sv0, tv0)); fma4(a01, wa.x, actv(u01, sv1, tv1));
            fma4(a00, wa.y, actv(u10, sv0, tv0)); fma4(a01, wa.y, actv(u11, sv1, tv1));
            fma4(a00, wa.z, actv(u20, sv0, tv0)); fma4(a01, wa.z, actv(u21, sv1, tv1));
            fma4(a00, wa.w, actv(u30, sv0, tv0)); fma4(a01, wa.w, actv(u31, sv1, tv1));
            fma4(a10, wb.x, actv(t00, sv0, tv0)); fma4(a11, wb.x, actv(t01, sv1, tv1));
            fma4(a10, wb.y, actv(t10, sv0, tv0)); fma4(a11, wb.y, actv(t11, sv1, tv1));
            fma4(a10, wb.z, actv(t20, sv0, tv0)); fma4(a11, wb.z, actv(t21, sv1, tv1));
            fma4(a10, wb.w, actv(t30, sv0, tv0)); fma4(a11, wb.w, actv(t31, sv1, tv1));
        }
        int row0 = (2 * pr + 0) * 8 + bi8;
        int row1 = (2 * pr + 1) * 8 + bi8;
        *(float4*)(Aw + row0 * ALS + ch0)     = a00;
        *(float4*)(Aw + row0 * ALS + ch0 + 4) = a01;
        *(float4*)(Aw + row1 * ALS + ch0)     = a10;
        *(float4*)(Aw + row1 * ALS + ch0 + 4) = a11;
    }
    // NO barrier: stage 2 reads only this wave's Aw slice.

    int colq = lane & 15, rowq = lane >> 4;   // rowq = node index 0..3
    int node = (rowq == 0) ? pid.x : (rowq == 1) ? pid.y : (rowq == 2) ? pid.z : pid.w;

    if (!SCORE) {
        const float4* __restrict__ W4 = (const float4*)W;
        float4 bb = ((const float4*)bias)[colq];
        float4 o[8];
#pragma unroll
        for (int i = 0; i < 8; ++i) o[i] = bb;
#pragma unroll 8
        for (int k = 0; k < 64; ++k) {
            float4 w4 = W4[k * 16 + colq];
#pragma unroll
            for (int i = 0; i < 8; ++i)
                fma4(o[i], Aw[(rowq * 8 + i) * ALS + k], w4);
        }
        if (node < NN) {
            float* ob = out + ((size_t)g * NN + node) * 512;
#pragma unroll
            for (int i = 0; i < 8; ++i)
                nt4((float4*)(ob + i * 64 + colq * 4), o[i]);
        }

        // stats: this thread covers 8 bi of ONE node; shfl sums over nodes
        float4 s4 = {0,0,0,0}, q4 = {0,0,0,0};
        if (node < NN) {
#pragma unroll
            for (int i = 0; i < 8; ++i) {
                s4.x += o[i].x; s4.y += o[i].y; s4.z += o[i].z; s4.w += o[i].w;
                q4.x = fmaf(o[i].x, o[i].x, q4.x); q4.y = fmaf(o[i].y, o[i].y, q4.y);
                q4.z = fmaf(o[i].z, o[i].z, q4.z); q4.w = fmaf(o[i].w, o[i].w, q4.w);
            }
        }
        s4.x += __shfl_xor(s4.x, 16); s4.y += __shfl_xor(s4.y, 16);
        s4.z += __shfl_xor(s4.z, 16); s4.w += __shfl_xor(s4.w, 16);
        q4.x += __shfl_xor(q4.x, 16); q4.y += __shfl_xor(q4.y, 16);
        q4.z += __shfl_xor(q4.z, 16); q4.w += __shfl_xor(q4.w, 16);
        s4.x += __shfl_xor(s4.x, 32); s4.y += __shfl_xor(s4.y, 32);
        s4.z += __shfl_xor(s4.z, 32); s4.w += __shfl_xor(s4.w, 32);
        q4.x += __shfl_xor(q4.x, 32); q4.y += __shfl_xor(q4.y, 32);
        q4.z += __shfl_xor(q4.z, 32); q4.w += __shfl_xor(q4.w, 32);
        __syncthreads();   // all waves done with As -> reuse as scratch
        if (lane < 16) {
            float* S = As + wid * 128;
            *(float4*)(S + lane * 8) = s4;
            *(float4*)(S + lane * 8 + 4) = q4;
        }
        __syncthreads();
        if (tid < 64) {
            int cq = tid >> 2, comp = tid & 3;
            float s = 0.f, q = 0.f;
#pragma unroll
            for (int w = 0; w < 4; ++w) {
                s += As[w * 128 + cq * 8 + comp];
                q += As[w * 128 + cq * 8 + 4 + comp];
            }
            float* sl = stats + (blockIdx.x & (NSLOT - 1)) * 128;
            atomicAdd(&sl[tid], s);
            atomicAdd(&sl[64 + tid], q);
        }
    } else {
        // agg copy from LDS + compact relu'd score (ch 63)
        if (node < NN) {
            float* ob = out + ((size_t)g * NN + node) * 512;
#pragma unroll
            for (int i = 0; i < 8; ++i)
                nt4((float4*)(ob + i * 64 + colq * 4),
                    *(const float4*)(Aw + (rowq * 8 + i) * ALS + colq * 4));
        }
        if (lane < 32) {
            int q = lane >> 3;
            int nd = (q == 0) ? pid.x : (q == 1) ? pid.y : (q == 2) ? pid.z : pid.w;
            if (nd < NN) {
                float s = bias[63];
                const float* Ar = Aw + lane * ALS;   // row (q*8 + lane&7) == lane
#pragma unroll 8
                for (int k = 0; k < 64; ++k)
                    s = fmaf(Ar[k], W[k * 64 + 63], s);
                score[((size_t)g * NN + nd) * 8 + (lane & 7)] = fmaxf(s, 0.f);
            }
        }
    }
}

// ---------------- sort-pool (blocks 0..31) + bnfin (block 32) ----------------
__global__ __launch_bounds__(1024) void k_toppool(const float* __restrict__ sc, int* order,
        const float* __restrict__ stats,
        const float* __restrict__ g0, const float* __restrict__ be0,
        const float* __restrict__ g1, const float* __restrict__ be1,
        float* __restrict__ st) {
    __shared__ unsigned long long wbest[16];
    __shared__ unsigned long long winner;
    int tid = threadIdx.x;
    if (blockIdx.x == NB) {
        if (tid < 128) {
            int c = tid & 63, layer = tid >> 6;
            const float* sb = stats + layer * NSLOT * 128;
            float su = 0.f, qu = 0.f;
#pragma unroll
            for (int s = 0; s < NSLOT; ++s) {
                su += sb[s * 128 + c];
                qu += sb[s * 128 + 64 + c];
            }
            const float inv = 1.0f / (float)(NB * NN);
            float mu = su * inv;
            float var = qu * inv - mu * mu;
            float g = layer ? g1[c] : g0[c];
            float be = layer ? be1[c] : be0[c];
            float scv = g / sqrtf(var + 1e-5f);
            st[layer * 128 + c] = scv;
            st[layer * 128 + 64 + c] = fmaf(-mu, scv, be);
        }
        return;
    }
    int b = blockIdx.x;
    int g4 = b >> 3, bi8 = b & 7;
    int lane = tid & 63, wid = tid >> 6;
    unsigned long long key[5];
#pragma unroll
    for (int j = 0; j < 5; ++j) {
        int n = tid + j * 1024;
        unsigned long long k = 0;
        if (n < NN) {
            float v = sc[((size_t)g4 * NN + n) * 8 + bi8];   // already relu'd
            k = ((unsigned long long)__float_as_uint(v) << 32) | (unsigned int)(NN - n);
        }
        key[j] = k;
    }
    for (int k = 0; k < KPOOL; ++k) {
        unsigned long long best = key[0];
#pragma unroll
        for (int j = 1; j < 5; ++j) best = (key[j] > best) ? key[j] : best;
#pragma unroll
        for (int off = 1; off < 64; off <<= 1) {
            unsigned long long o = __shfl_xor(best, off);
            best = (o > best) ? o : best;
        }
        if (lane == 0) wbest[wid] = best;
        __syncthreads();
        if (tid == 0) {
            unsigned long long w = wbest[0];
#pragma unroll
            for (int i = 1; i < 16; ++i) w = (wbest[i] > w) ? wbest[i] : w;
            winner = w;
            order[b * KPOOL + k] = NN - (int)(w & 0xFFFFFFFFu);
        }
        __syncthreads();
        int n = NN - (int)(winner & 0xFFFFFFFFu);
        if ((n & 1023) == tid) key[n >> 10] = 0;   // remove winner (owner thread)
    }
}

// ---------------- gather selected nodes into flat (B, 6241) ----------------
__global__ void k_gather(const float* __restrict__ xt,
                         const float* __restrict__ h1, const float* __restrict__ h2,
                         const float* __restrict__ agg,
                         const float* __restrict__ W2, const float* __restrict__ b2,
                         const float* __restrict__ st, const float* __restrict__ age,
                         const int* __restrict__ order, float* __restrict__ flat) {
    int bk = blockIdx.x;
    int b = bk / KPOOL, k = bk % KPOOL;
    int n = order[bk];
    int g8 = b >> 2, bi4 = b & 3;             // xt layout (G8,N,4,16)
    size_t hoff = ((size_t)(b >> 3) * NN + n) * 8 + (b & 7);   // G4 layout row
    int f = threadIdx.x;
    float val = 0.f;
    if (f < DIN) {
        val = xt[(((size_t)g8 * NN + n) * GB + bi4) * DIN + f];
    } else if (f < DIN + CH) {
        int c = f - DIN;
        val = fmaxf(fmaf(h1[hoff * 64 + c], st[c], st[64 + c]), 0.f);
    } else if (f < DIN + 2 * CH) {
        int c = f - DIN - CH;
        val = fmaxf(fmaf(h2[hoff * 64 + c], st[128 + c], st[192 + c]), 0.f);
    } else if (f < FTOT) {
        int c = f - DIN - 2 * CH;
        const float* __restrict__ Ar = agg + hoff * 64;
        float s = b2[c];
#pragma unroll 8
        for (int kk = 0; kk < 64; ++kk)
            s = fmaf(Ar[kk], W2[kk * 64 + c], s);   // Ar broadcast, W2 coalesced
        val = fmaxf(s, 0.f);
    }
    if (f < FTOT) flat[(size_t)b * FLATW + k * FTOT + f] = val;
    if (bk == 0 && f >= FTOT && f < FTOT + NB)
        flat[(size_t)(f - FTOT) * FLATW + (FLATW - 1)] = age[f - FTOT];
}

// ---------------- MLP head layer 1: hm += flat @ mW0 (k-split, atomics) ----------------
__global__ void k_head1(const float* __restrict__ flat, const float* __restrict__ mW0,
                        float* hm) {
    int tid = threadIdx.x;
    int j4 = (tid & 31) * 4;       // 32 groups * 4 = 128 cols
    int b0 = (tid >> 5) * 4;       // 8 groups * 4 = 32 rows
    int kbase = blockIdx.x * 64;
    float acc[4][4];
#pragma unroll
    for (int i = 0; i < 4; i++)
#pragma unroll
        for (int jj = 0; jj < 4; jj++) acc[i][jj] = 0.f;
    int kend = FLATW - kbase; if (kend > 64) kend = 64;
    for (int kk = 0; kk < kend; ++kk) {
        int k = kbase + kk;
        float4 w = *(const float4*)(mW0 + (size_t)k * NH + j4);
#pragma unroll
        for (int i = 0; i < 4; i++) {
            float fv = flat[(size_t)(b0 + i) * FLATW + k];
            acc[i][0] = fmaf(fv, w.x, acc[i][0]);
            acc[i][1] = fmaf(fv, w.y, acc[i][1]);
            acc[i][2] = fmaf(fv, w.z, acc[i][2]);
            acc[i][3] = fmaf(fv, w.w, acc[i][3]);
        }
    }
#pragma unroll
    for (int i = 0; i < 4; i++)
#pragma unroll
        for (int jj = 0; jj < 4; jj++)
            atomicAdd(&hm[(size_t)(b0 + i) * NH + j4 + jj], acc[i][jj]);
}

// ---------------- head layer 2 + log_softmax (4-way j-split) ----------------
__global__ void k_head2(const float* __restrict__ hm, const float* __restrict__ mb0,
                        const float* __restrict__ mW1, const float* __restrict__ mb1,
                        float* __restrict__ out) {
    __shared__ float part[256];
    __shared__ float vals[64];
    int tid = threadIdx.x;  // 256 = 32b * 2o * 4q
    int q = tid & 3, o = (tid >> 2) & 1, b = tid >> 3;
    float acc = 0.f;
    for (int j = q * 32; j < q * 32 + 32; ++j) {
        float hv = fmaxf(hm[b * NH + j] + mb0[j], 0.f);
        acc = fmaf(hv, mW1[j * 2 + o], acc);
    }
    part[tid] = acc;
    __syncthreads();
    if (tid < 64) {
        int b2 = tid >> 1, o2 = tid & 1;
        int base = (b2 << 3) + (o2 << 2);
        vals[tid] = part[base] + part[base + 1] + part[base + 2] + part[base + 3] + mb1[o2];
    }
    __syncthreads();
    if (tid < 64) {
        int b2 = tid >> 1;
        float v0 = vals[b2 * 2], v1 = vals[b2 * 2 + 1];
        float m = fmaxf(v0, v1);
        float lse = m + logf(expf(v0 - m) + expf(v1 - m));
        out[tid] = vals[tid] - lse;
    }
}

extern "C" void kernel_launch(void* const* d_in, const int* in_sizes, int n_in,
                              void* d_out, int out_size, void* d_ws, size_t ws_size,
                              hipStream_t stream) {
    const float* x    = (const float*)d_in[0];
    const float* age  = (const float*)d_in[1];
    const float* attr = (const float*)d_in[2];
    const float* W0   = (const float*)d_in[3];
    const float* b0   = (const float*)d_in[4];
    const float* W1   = (const float*)d_in[5];
    const float* b1   = (const float*)d_in[6];
    const float* W2   = (const float*)d_in[7];
    const float* b2   = (const float*)d_in[8];
    const float* g0   = (const float*)d_in[9];
    const float* be0  = (const float*)d_in[10];
    const float* g1   = (const float*)d_in[11];
    const float* be1  = (const float*)d_in[12];
    const float* mW0  = (const float*)d_in[13];
    const float* mb0  = (const float*)d_in[14];
    const float* mW1  = (const float*)d_in[15];
    const float* mb1  = (const float*)d_in[16];
    const int* erow   = (const int*)d_in[17];
    const int* ecol   = (const int*)d_in[18];
    float* out = (float*)d_out;

    // workspace layout (floats); all float4-aligned
    float* ws     = (float*)d_ws;
    float* deg    = ws;                                  // 5008
    float* dinv   = deg + 5008;                          // 5008
    int*   counts = (int*)(dinv + 5008);                 // 5008
    int*   rowptr = counts + 5008;                       // 5008
    int*   cursor = rowptr + 5008;                       // 5008
    int*   perm   = cursor + 5008;                       // 5008
    int*   csr_col= perm + 5008;                         // NEPAD
    float* csr_nv = (float*)(csr_col + NEPAD);           // NEPAD
    float* stats  = csr_nv + NEPAD;                      // 2*32*128 = 8192
    float* st     = stats + 2 * NSLOT * 128;             // 256 (s0,t0,s1,t1)
    float* sc     = st + 256;                            // 4*NN*8 = 160000 (scores)
    int*   order  = (int*)(sc + NB * NN);                // 960
    float* flat   = (float*)(order + 960);               // 32*6241
    float* hm     = flat + (size_t)NB * FLATW;           // 4096
    float* xt     = hm + 4096;                           // (G8,N,4,16)
    float* h1     = xt + (size_t)NB * NN * DIN;          // (G4,N,8,64) each
    float* h2     = h1 + (size_t)NB * NN * CH;
    float* agg    = h2 + (size_t)NB * NN * CH;

    // graph build: scan+sort+transpose share one dispatch (concurrent roles)
    k_init<<<32, 256, 0, stream>>>(deg, counts, stats, hm, perm);
    k_edges<<<NEB, 256, 0, stream>>>(attr, erow, deg, counts);
    k_phase1<<<2 + (NB * NN + 1023) / 1024, 1024, 0, stream>>>(counts, deg, rowptr, cursor, dinv, perm, x, xt);
    k_build<<<(NE + NN + 1023) / 1024, 1024, 0, stream>>>(erow, ecol, attr, dinv, counts, rowptr, cursor, csr_col, csr_nv);

    // layer 0 (G8 read, G4 write) then G4 wide-row CIN64 layers
    k_l16<<<NCHUNK * NG, 256, 0, stream>>>(xt, W0, b0, rowptr, csr_col, csr_nv, dinv, perm, h1, stats);
    k_l64<0><<<NCHUNK * 4, 256, 0, stream>>>(h1, stats, g0, be0, W1, b1, rowptr, csr_col, csr_nv, dinv, perm, h2, stats + NSLOT * 128, nullptr);
    k_l64<1><<<NCHUNK * 4, 256, 0, stream>>>(h2, stats + NSLOT * 128, g1, be1, W2, b2, rowptr, csr_col, csr_nv, dinv, perm, agg, nullptr, sc);

    // sort-pool (+fused bnfin) + gather (deferred GEMM) + head
    k_toppool<<<NB + 1, 1024, 0, stream>>>(sc, order, stats, g0, be0, g1, be1, st);
    k_gather<<<NB * KPOOL, 256, 0, stream>>>(xt, h1, h2, agg, W2, b2, st, age, order, flat);
    k_head1<<<(FLATW + 63) / 64, 256, 0, stream>>>(flat, mW0, hm);
    k_head2<<<1, 256, 0, stream>>>(hm, mb0, mW1, mb1, out);
}

// Round 10
// 316.481 us; speedup vs baseline: 1.3390x; 1.2406x over previous
//
#include <hip/hip_runtime.h>
#include <math.h>

// Problem constants (from reference setup_inputs)
#define NN    5000      // nodes
#define NE    80000     // edges
#define NB    32        // batch
#define DIN   16        // input feat
#define CH    64        // conv channels
#define KPOOL 30
#define FTOT  208      // 16 + 3*64
#define FLATW 6241     // KPOOL*FTOT + 1
#define NH    128      // MLP hidden
#define NG    8        // batch groups (one per XCD)
#define GB    4        // batches per group
#define NPB   16       // nodes per block (4 per wave)
#define NCHUNK 313     // node chunks (blocks per group)
#define NPAD  5008     // perm array size
#define NEPAD (NE + 4 * NN)   // CSR rows padded to multiple of 4
#define NSLOT 32       // stats atomic-spread slots

// Journal: R19 ordering / R20+R24 occupancy: dead. R21 CSR rotate: neutral.
// R22 act-hoist: -43% VALU -> -5% dur. R26 serial-merge: 354 -> 348.6 (best).
// R27/28 batch-half: FETCH 114->13MB but pass-doubling loses (layers are
// iteration-latency bound). R29 wide rows: VGPR-capped load serialization +
// 2-XCD slab thrash (FETCH 227MB) -> 96us. LAYER CONFIG MAPPED: G8/1KB rows
// (g=blockIdx&7 -> slab pinned to one XCD) at 73us IS the fp32 gather floor.
// R30 (this): kill the 3rd conv pass ALGEBRAICALLY. score ch-63 commutes
// through the spmm: z[b,n]=act(h2row)�W2[:,63] (streaming k_z), then score =
// relu(sparse-agg of SCALAR z + self + b2[63]) (k_score, 16B gathers from an
// 80KB/group slab). Full 64-ch agg rows needed only for the 960 SELECTED
// nodes -> moved into k_gather (4-way edge-split + LDS row + GEMM).
// Saves 73us pass + 41MB agg writes for ~22us of new work.

// ---------------- setup kernels ----------------

__global__ void k_init(float* deg, int* counts, float* stats, float* hm, int* perm) {
    int i = blockIdx.x * 256 + threadIdx.x;
    if (i < NN) { deg[i] = 1.0f; counts[i] = 0; }   // deg starts at self-loop value 1
    if (i < 2 * NSLOT * 128) stats[i] = 0.0f;       // [2 layers][32 slots][128]
    if (i < 4096) hm[i] = 0.0f;
    if (i >= NN && i < NPAD) perm[i] = NN;          // tail -> invalid marker
}

#define NEB 313
__global__ void k_edges(const float* __restrict__ attr, const int* __restrict__ erow,
                        float* deg, int* counts) {
    int e = blockIdx.x * 256 + threadIdx.x;
    if (e < NE) {
        int r = erow[e];
        atomicAdd(&deg[r], attr[e]);
        atomicAdd(&counts[r], 1);
    }
}

// merged concurrent phase: block 0 = prefix scan, block 1 = counting sort,
// blocks 2.. = x transpose (serial roles hide under the wide transpose).
__global__ __launch_bounds__(1024) void k_phase1(
        const int* __restrict__ counts, const float* __restrict__ deg,
        int* rowptr, int* cursor, float* dinv, int* perm,
        const float* __restrict__ x, float* __restrict__ xt) {
    __shared__ int wsum[16], woff[16];
    __shared__ int carry_sh;
    __shared__ int hist[256];
    int t = threadIdx.x;
    if (blockIdx.x >= 2) {
        int idx = (blockIdx.x - 2) * 1024 + t;
        if (idx >= NB * NN) return;
        int b = idx / NN, n = idx % NN;
        int g = b >> 2, bi = b & 3;
        const float4* src = (const float4*)(x + (size_t)idx * DIN);
        float4* dst = (float4*)(xt + (((size_t)g * NN + n) * GB + bi) * DIN);
        dst[0] = src[0]; dst[1] = src[1]; dst[2] = src[2]; dst[3] = src[3];
        return;
    }
    if (blockIdx.x == 0) {
        int lane = t & 63, wid = t >> 6;
        if (t == 0) carry_sh = 0;
        __syncthreads();
        for (int base = 0; base < NN; base += 1024) {
            int carry = carry_sh;
            int i = base + t;
            int v = 0;
            if (i < NN) {
                v = (counts[i] + 3) & ~3;
                dinv[i] = 1.0f / sqrtf(deg[i]);   // deg >= 1 always
            }
            int s = v;
#pragma unroll
            for (int off = 1; off < 64; off <<= 1) {
                int o = __shfl_up(s, off);
                if (lane >= off) s += o;
            }
            if (lane == 63) wsum[wid] = s;
            __syncthreads();
            if (t < 16) {
                int w = wsum[t];
#pragma unroll
                for (int off = 1; off < 16; off <<= 1) {
                    int o = __shfl_up(w, off);
                    if (t >= off) w += o;
                }
                woff[t] = w;
            }
            __syncthreads();
            int inc = s + (wid > 0 ? woff[wid - 1] : 0) + carry;
            if (i < NN) {
                rowptr[i + 1] = inc;
                cursor[i] = inc - v;
            }
            if (t == 1023) carry_sh = carry + woff[15];
            __syncthreads();
        }
        if (t == 0) rowptr[0] = 0;
    } else {
        if (t < 256) hist[t] = 0;
        __syncthreads();
        for (int i = t; i < NN; i += 1024) {
            int b = 255 - min(((counts[i] + 3) & ~3) >> 2, 255);
            atomicAdd(&hist[b], 1);
        }
        __syncthreads();
        int mycnt = (t < 256) ? hist[t] : 0;
        for (int off = 1; off < 256; off <<= 1) {
            int v = (t < 256 && t >= off) ? hist[t - off] : 0;
            __syncthreads();
            if (t < 256) hist[t] += v;
            __syncthreads();
        }
        if (t < 256) hist[t] -= mycnt;
        __syncthreads();
        for (int i = t; i < NN; i += 1024) {
            int b = 255 - min(((counts[i] + 3) & ~3) >> 2, 255);
            int pos = atomicAdd(&hist[b], 1);
            perm[pos] = i;
        }
    }
}

__global__ __launch_bounds__(1024) void k_build(
        const int* __restrict__ erow, const int* __restrict__ ecol,
        const float* __restrict__ attr, const float* __restrict__ dinv,
        const int* __restrict__ counts, const int* __restrict__ rowptr,
        int* cursor, int* csr_col, float* csr_nv) {
    int t = blockIdx.x * 1024 + threadIdx.x;
    if (t < NE) {
        int r = erow[t], c = ecol[t];
        int pos = atomicAdd(&cursor[r], 1);
        csr_col[pos] = c;
        csr_nv[pos] = dinv[r] * attr[t] * dinv[c];
    } else if (t - NE < NN) {
        int i = t - NE;
        int cnt = counts[i];
        int pcnt = (cnt + 3) & ~3;
        int base = rowptr[i + 1] - pcnt;
        for (int p = base + cnt; p < base + pcnt; ++p) { csr_col[p] = i; csr_nv[p] = 0.0f; }
    }
}

// ---------------- helpers ----------------
template<int ACT>
__device__ __forceinline__ float4 actv(float4 v, float4 s, float4 t) {
    if (ACT) {
        v.x = fmaxf(fmaf(v.x, s.x, t.x), 0.f);
        v.y = fmaxf(fmaf(v.y, s.y, t.y), 0.f);
        v.z = fmaxf(fmaf(v.z, s.z, t.z), 0.f);
        v.w = fmaxf(fmaf(v.w, s.w, t.w), 0.f);
    }
    return v;
}
__device__ __forceinline__ void fma4(float4& a, float w, float4 v) {
    a.x = fmaf(w, v.x, a.x); a.y = fmaf(w, v.y, a.y);
    a.z = fmaf(w, v.z, a.z); a.w = fmaf(w, v.w, a.w);
}

// ---------------- fused GCN layer (R0 proven base — at gather roofline) ------
template<int CIN, int ACT, int STATS>
__global__ __launch_bounds__(256) void k_layer(
        const float* __restrict__ in, const float* __restrict__ bnstats,
        const float* __restrict__ gamma, const float* __restrict__ beta,
        const float* __restrict__ W, const float* __restrict__ bias,
        const int* __restrict__ rowptr, const int* __restrict__ csr_col,
        const float* __restrict__ csr_nv, const float* __restrict__ dinv,
        const int* __restrict__ perm,
        float* __restrict__ out, float* __restrict__ stats) {
    constexpr int ALS = (CIN == 64) ? 68 : 20;
    __shared__ float As[4 * 16 * ALS];
    __shared__ float stl[ACT ? 128 : 4];
    int tid = threadIdx.x;
    int wid = tid >> 6, lane = tid & 63;
    int g = blockIdx.x & 7;                      // XCD round-robin
    int nb = (blockIdx.x >> 3) * NPB;
    int base = nb + wid * 4;
    float* Aw = As + wid * 16 * ALS;
    const int4 pid = *(const int4*)(perm + base);   // 4 node ids (degree-sorted)

    if (ACT) {
        if (tid < 64) {
            float su = 0.f, qu = 0.f;
#pragma unroll
            for (int s = 0; s < NSLOT; ++s) {
                su += bnstats[s * 128 + tid];
                qu += bnstats[s * 128 + 64 + tid];
            }
            const float inv = 1.0f / (float)(NB * NN);
            float mu = su * inv;
            float var = qu * inv - mu * mu;
            float sc = gamma[tid] / sqrtf(var + 1e-5f);
            stl[tid] = sc;
            stl[64 + tid] = fmaf(-mu, sc, beta[tid]);
        }
        __syncthreads();
    }

    if (CIN == 64) {
        const float4* __restrict__ in4 = (const float4*)in + (size_t)g * NN * 64;
        int c4 = lane & 15, bi = lane >> 4;
        float4 sv = {1.f,1.f,1.f,1.f}, tv = {0.f,0.f,0.f,0.f};
        if (ACT) { sv = ((const float4*)stl)[c4]; tv = ((const float4*)(stl + 64))[c4]; }
#pragma unroll
        for (int pr = 0; pr < 2; ++pr) {
            int id0 = (pr == 0) ? pid.x : pid.z;
            int id1 = (pr == 0) ? pid.y : pid.w;
            bool vn0 = id0 < NN, vn1 = id1 < NN;
            int rc0 = vn0 ? id0 : 0, rc1 = vn1 ? id1 : 0;
            float dd0 = dinv[rc0]; dd0 *= dd0;
            float dd1 = dinv[rc1]; dd1 *= dd1;
            float4 a0 = {0.f,0.f,0.f,0.f}, a1 = {0.f,0.f,0.f,0.f};
            {
                float4 v0 = actv<ACT>(in4[(size_t)rc0 * 64 + lane], sv, tv);
                float4 v1 = actv<ACT>(in4[(size_t)rc1 * 64 + lane], sv, tv);
                if (vn0) { a0.x = dd0 * v0.x; a0.y = dd0 * v0.y; a0.z = dd0 * v0.z; a0.w = dd0 * v0.w; }
                if (vn1) { a1.x = dd1 * v1.x; a1.y = dd1 * v1.y; a1.z = dd1 * v1.z; a1.w = dd1 * v1.w; }
            }
            int p0a = rowptr[rc0], na = vn0 ? (rowptr[rc0 + 1] - p0a) >> 2 : 0;
            int p0b = rowptr[rc1], nbv = vn1 ? (rowptr[rc1 + 1] - p0b) >> 2 : 0;
            int mx = max(na, nbv);
            for (int bb = 0; bb < mx; ++bb) {
                int ea = min(p0a + 4 * bb, NEPAD - 4);
                int eb = min(p0b + 4 * bb, NEPAD - 4);
                bool va = bb < na, vb = bb < nbv;
                int4   ca = *(const int4*)(csr_col + ea);
                float4 wa = *(const float4*)(csr_nv + ea);
                int4   cb = *(const int4*)(csr_col + eb);
                float4 wb = *(const float4*)(csr_nv + eb);
                if (!va) { wa.x = 0.f; wa.y = 0.f; wa.z = 0.f; wa.w = 0.f;
                           ca.x = 0; ca.y = 0; ca.z = 0; ca.w = 0; }   // poisoned tail
                if (!vb) { wb.x = 0.f; wb.y = 0.f; wb.z = 0.f; wb.w = 0.f;
                           cb.x = 0; cb.y = 0; cb.z = 0; cb.w = 0; }
                float4 u0 = in4[(size_t)ca.x * 64 + lane];
                float4 u1 = in4[(size_t)ca.y * 64 + lane];
                float4 u2 = in4[(size_t)ca.z * 64 + lane];
                float4 u3 = in4[(size_t)ca.w * 64 + lane];
                float4 t0 = in4[(size_t)cb.x * 64 + lane];
                float4 t1 = in4[(size_t)cb.y * 64 + lane];
                float4 t2 = in4[(size_t)cb.z * 64 + lane];
                float4 t3 = in4[(size_t)cb.w * 64 + lane];
                fma4(a0, wa.x, actv<ACT>(u0, sv, tv));
                fma4(a0, wa.y, actv<ACT>(u1, sv, tv));
                fma4(a0, wa.z, actv<ACT>(u2, sv, tv));
                fma4(a0, wa.w, actv<ACT>(u3, sv, tv));
                fma4(a1, wb.x, actv<ACT>(t0, sv, tv));
                fma4(a1, wb.y, actv<ACT>(t1, sv, tv));
                fma4(a1, wb.z, actv<ACT>(t2, sv, tv));
                fma4(a1, wb.w, actv<ACT>(t3, sv, tv));
            }
            *(float4*)(Aw + ((pr * 2 + 0) * 4 + bi) * ALS + c4 * 4) = a0;
            *(float4*)(Aw + ((pr * 2 + 1) * 4 + bi) * ALS + c4 * 4) = a1;
        }
    } else {
        const float* __restrict__ inr = in + (size_t)g * NN * 64;   // row = 64 floats
        int ids[4] = {pid.x, pid.y, pid.z, pid.w};
#pragma unroll
        for (int i = 0; i < 4; ++i) {
            int r = ids[i];
            float a = 0.f;
            if (r < NN) {
                float d = dinv[r];
                a = d * d * inr[(size_t)r * 64 + lane];
                int p0 = rowptr[r], p1 = rowptr[r + 1];
                for (int e = p0; e < p1; e += 4) {
                    int4   cc = *(const int4*)(csr_col + e);
                    float4 ww = *(const float4*)(csr_nv + e);
                    float v0 = inr[(size_t)cc.x * 64 + lane];
                    float v1 = inr[(size_t)cc.y * 64 + lane];
                    float v2 = inr[(size_t)cc.z * 64 + lane];
                    float v3 = inr[(size_t)cc.w * 64 + lane];
                    a = fmaf(ww.x, v0, a);
                    a = fmaf(ww.y, v1, a);
                    a = fmaf(ww.z, v2, a);
                    a = fmaf(ww.w, v3, a);
                }
            }
            Aw[(i * 4 + (lane >> 4)) * ALS + (lane & 15)] = a;
        }
    }
    // NO __syncthreads here: stage 2 reads only this wave's Aw slice.

    int colq = lane & 15, rowq = lane >> 4;
    int node = (rowq == 0) ? pid.x : (rowq == 1) ? pid.y : (rowq == 2) ? pid.z : pid.w;

    // ---- stage 2: per-wave GEMM; thread -> (node rowq, colq) ----
    const float4* __restrict__ W4 = (const float4*)W;
    float4 bb = ((const float4*)bias)[colq];
    float4 o[4];
#pragma unroll
    for (int i = 0; i < 4; ++i) o[i] = bb;
#pragma unroll 8
    for (int k = 0; k < CIN; ++k) {
        float4 w4 = W4[k * 16 + colq];
#pragma unroll
        for (int i = 0; i < 4; ++i) {
            float a = Aw[(rowq * 4 + i) * ALS + k];
            fma4(o[i], a, w4);
        }
    }
    if (node < NN) {
        float4* __restrict__ op = (float4*)(out + ((size_t)g * NN + node) * 256);
#pragma unroll
        for (int i = 0; i < 4; ++i) op[i * 16 + colq] = o[i];
    }

    if (STATS) {
        float4 s4 = {0,0,0,0}, q4 = {0,0,0,0};
        if (node < NN) {
#pragma unroll
            for (int i = 0; i < 4; ++i) {
                s4.x += o[i].x; s4.y += o[i].y; s4.z += o[i].z; s4.w += o[i].w;
                q4.x = fmaf(o[i].x, o[i].x, q4.x); q4.y = fmaf(o[i].y, o[i].y, q4.y);
                q4.z = fmaf(o[i].z, o[i].z, q4.z); q4.w = fmaf(o[i].w, o[i].w, q4.w);
            }
        }
        s4.x += __shfl_xor(s4.x, 16); s4.y += __shfl_xor(s4.y, 16);
        s4.z += __shfl_xor(s4.z, 16); s4.w += __shfl_xor(s4.w, 16);
        q4.x += __shfl_xor(q4.x, 16); q4.y += __shfl_xor(q4.y, 16);
        q4.z += __shfl_xor(q4.z, 16); q4.w += __shfl_xor(q4.w, 16);
        s4.x += __shfl_xor(s4.x, 32); s4.y += __shfl_xor(s4.y, 32);
        s4.z += __shfl_xor(s4.z, 32); s4.w += __shfl_xor(s4.w, 32);
        q4.x += __shfl_xor(q4.x, 32); q4.y += __shfl_xor(q4.y, 32);
        q4.z += __shfl_xor(q4.z, 32); q4.w += __shfl_xor(q4.w, 32);
        __syncthreads();   // all waves done with As -> reuse as scratch
        if (lane < 16) {
            float* S = As + wid * 128;
            *(float4*)(S + lane * 8) = s4;
            *(float4*)(S + lane * 8 + 4) = q4;
        }
        __syncthreads();
        if (tid < 64) {
            int cq = tid >> 2, comp = tid & 3;
            float s = 0.f, q = 0.f;
#pragma unroll
            for (int w = 0; w < 4; ++w) {
                s += As[w * 128 + cq * 8 + comp];
                q += As[w * 128 + cq * 8 + 4 + comp];
            }
            float* sl = stats + (blockIdx.x & (NSLOT - 1)) * 128;
            atomicAdd(&sl[tid], s);
            atomicAdd(&sl[64 + tid], q);
        }
    }
}

// ---------------- k_z: z[b,n] = act(h2 row) . W2[:,63] (streaming) ----------
#define ZBLK 2048
__global__ __launch_bounds__(256) void k_z(
        const float* __restrict__ h2, const float* __restrict__ bnstats,
        const float* __restrict__ gamma, const float* __restrict__ beta,
        const float* __restrict__ W2, float* __restrict__ z) {
    __shared__ float stl[128];
    __shared__ float w63[64];
    int tid = threadIdx.x;
    if (tid < 64) {
        float su = 0.f, qu = 0.f;
#pragma unroll
        for (int s = 0; s < NSLOT; ++s) {
            su += bnstats[s * 128 + tid];
            qu += bnstats[s * 128 + 64 + tid];
        }
        const float inv = 1.0f / (float)(NB * NN);
        float mu = su * inv;
        float var = qu * inv - mu * mu;
        float sc = gamma[tid] / sqrtf(var + 1e-5f);
        stl[tid] = sc;
        stl[64 + tid] = fmaf(-mu, sc, beta[tid]);
        w63[tid] = W2[tid * 64 + 63];
    }
    __syncthreads();
    int lane = tid & 63, wid = tid >> 6;
    int c4 = lane & 15;
    float4 sv = ((const float4*)stl)[c4];
    float4 tv = ((const float4*)(stl + 64))[c4];
    float4 w4 = ((const float4*)w63)[c4];
    const int total = NB * NN;   // 256B rows of h2
    for (int base = blockIdx.x * 16; base < total; base += ZBLK * 16) {
        int row = base + wid * 4 + (lane >> 4);
        float s = 0.f;
        if (row < total) {
            float4 v = ((const float4*)h2)[(size_t)row * 16 + c4];
            v.x = fmaxf(fmaf(v.x, sv.x, tv.x), 0.f);
            v.y = fmaxf(fmaf(v.y, sv.y, tv.y), 0.f);
            v.z = fmaxf(fmaf(v.z, sv.z, tv.z), 0.f);
            v.w = fmaxf(fmaf(v.w, sv.w, tv.w), 0.f);
            s = v.x * w4.x + v.y * w4.y + v.z * w4.z + v.w * w4.w;
        }
        s += __shfl_xor(s, 1);
        s += __shfl_xor(s, 2);
        s += __shfl_xor(s, 4);
        s += __shfl_xor(s, 8);
        if ((lane & 15) == 0 && row < total) z[row] = s;
    }
}

// ---------------- k_score: sparse agg of scalar z -> sc (wave per node) -----
__global__ __launch_bounds__(256) void k_score(
        const float* __restrict__ z, const float* __restrict__ b2,
        const int* __restrict__ rowptr, const int* __restrict__ csr_col,
        const float* __restrict__ csr_nv, const float* __restrict__ dinv,
        float* __restrict__ sc) {
    int tid = threadIdx.x;
    int wid = tid >> 6, lane = tid & 63;
    int g = blockIdx.x & 7;
    int nd = (blockIdx.x >> 3) * 4 + wid;   // 1250*4 = 5000 exactly
    if (nd >= NN) return;                   // no barriers below
    const float4* __restrict__ z4 = (const float4*)z + (size_t)g * NN;
    int p0 = rowptr[nd], p1 = rowptr[nd + 1];
    float4 a = {0.f, 0.f, 0.f, 0.f};
    for (int e = p0 + lane; e < p1; e += 64) {
        int col = csr_col[e];
        float nv = csr_nv[e];        // pad entries have nv=0, col=self: safe
        float4 zv = z4[col];
        fma4(a, nv, zv);
    }
#pragma unroll
    for (int off = 1; off < 64; off <<= 1) {
        a.x += __shfl_xor(a.x, off);
        a.y += __shfl_xor(a.y, off);
        a.z += __shfl_xor(a.z, off);
        a.w += __shfl_xor(a.w, off);
    }
    if (lane == 0) {
        float d = dinv[nd]; d *= d;
        float4 zs = z4[nd];
        float bb = b2[63];
        float4 o;
        o.x = fmaxf(fmaf(d, zs.x, a.x) + bb, 0.f);
        o.y = fmaxf(fmaf(d, zs.y, a.y) + bb, 0.f);
        o.z = fmaxf(fmaf(d, zs.z, a.z) + bb, 0.f);
        o.w = fmaxf(fmaf(d, zs.w, a.w) + bb, 0.f);
        ((float4*)sc)[(size_t)g * NN + nd] = o;
    }
}

// ---------------- sort-pool (blocks 0..31) + bnfin (block 32) ----------------
__global__ __launch_bounds__(1024) void k_toppool(const float* __restrict__ sc, int* order,
        const float* __restrict__ stats,
        const float* __restrict__ g0, const float* __restrict__ be0,
        const float* __restrict__ g1, const float* __restrict__ be1,
        float* __restrict__ st) {
    __shared__ unsigned long long wbest[16];
    __shared__ unsigned long long winner;
    int tid = threadIdx.x;
    if (blockIdx.x == NB) {
        if (tid < 128) {
            int c = tid & 63, layer = tid >> 6;
            const float* sb = stats + layer * NSLOT * 128;
            float su = 0.f, qu = 0.f;
#pragma unroll
            for (int s = 0; s < NSLOT; ++s) {
                su += sb[s * 128 + c];
                qu += sb[s * 128 + 64 + c];
            }
            const float inv = 1.0f / (float)(NB * NN);
            float mu = su * inv;
            float var = qu * inv - mu * mu;
            float g = layer ? g1[c] : g0[c];
            float be = layer ? be1[c] : be0[c];
            float scv = g / sqrtf(var + 1e-5f);
            st[layer * 128 + c] = scv;
            st[layer * 128 + 64 + c] = fmaf(-mu, scv, be);
        }
        return;
    }
    int b = blockIdx.x;
    int g = b >> 2, bi = b & 3;
    int lane = tid & 63, wid = tid >> 6;
    unsigned long long key[5];
#pragma unroll
    for (int j = 0; j < 5; ++j) {
        int n = tid + j * 1024;
        unsigned long long k = 0;
        if (n < NN) {
            float v = sc[((size_t)g * NN + n) * GB + bi];   // already relu'd
            k = ((unsigned long long)__float_as_uint(v) << 32) | (unsigned int)(NN - n);
        }
        key[j] = k;
    }
    for (int k = 0; k < KPOOL; ++k) {
        unsigned long long best = key[0];
#pragma unroll
        for (int j = 1; j < 5; ++j) best = (key[j] > best) ? key[j] : best;
#pragma unroll
        for (int off = 1; off < 64; off <<= 1) {
            unsigned long long o = __shfl_xor(best, off);
            best = (o > best) ? o : best;
        }
        if (lane == 0) wbest[wid] = best;
        __syncthreads();
        if (tid == 0) {
            unsigned long long w = wbest[0];
#pragma unroll
            for (int i = 1; i < 16; ++i) w = (wbest[i] > w) ? wbest[i] : w;
            winner = w;
            order[b * KPOOL + k] = NN - (int)(w & 0xFFFFFFFFu);
        }
        __syncthreads();
        int n = NN - (int)(winner & 0xFFFFFFFFu);
        if ((n & 1023) == tid) key[n >> 10] = 0;   // remove winner (owner thread)
    }
}

// ---------------- gather selected nodes into flat (B, 6241) ----------------
// Now also AGGREGATES the h3 row for this (b,node) from act(h2) (only 960
// pairs need it — R30), then does the 64x64 GEMM from LDS.
__global__ void k_gather(const float* __restrict__ xt, const float* __restrict__ h1,
                         const float* __restrict__ h2,
                         const float* __restrict__ W2, const float* __restrict__ b2,
                         const float* __restrict__ st, const float* __restrict__ age,
                         const int* __restrict__ rowptr, const int* __restrict__ csr_col,
                         const float* __restrict__ csr_nv, const float* __restrict__ dinv,
                         const int* __restrict__ order, float* __restrict__ flat) {
    __shared__ float aggP[4][64];
    __shared__ float aggRow[64];
    int bk = blockIdx.x;
    int b = bk / KPOOL, k = bk % KPOOL;
    int n = order[bk];
    int g = b >> 2, bi = b & 3;
    size_t node = (size_t)g * NN + n;
    int tid = threadIdx.x;
    // ---- phase 1: 4-way edge-split aggregation of act(h2) row ----
    {
        int ep = tid >> 6, c = tid & 63;
        float sc1 = st[128 + c], sh1 = st[192 + c];
        float a = 0.f;
        if (ep == 0) {
            float d = dinv[n];
            float v = h2[(node * GB + bi) * CH + c];
            a = d * d * fmaxf(fmaf(v, sc1, sh1), 0.f);
        }
        int p0 = rowptr[n], p1 = rowptr[n + 1];
        for (int e = p0 + ep; e < p1; e += 4) {
            int col = csr_col[e];
            float nv = csr_nv[e];    // pad entries nv=0: safe
            float v = h2[(((size_t)g * NN + col) * GB + bi) * CH + c];
            a += nv * fmaxf(fmaf(v, sc1, sh1), 0.f);
        }
        aggP[ep][c] = a;
    }
    __syncthreads();
    if (tid < 64) aggRow[tid] = aggP[0][tid] + aggP[1][tid] + aggP[2][tid] + aggP[3][tid];
    __syncthreads();
    // ---- phase 2: feature assembly ----
    int f = tid;
    float val = 0.f;
    if (f < DIN) {
        val = xt[(node * GB + bi) * DIN + f];
    } else if (f < DIN + CH) {
        int c = f - DIN;
        val = fmaxf(fmaf(h1[(node * GB + bi) * CH + c], st[c], st[64 + c]), 0.f);
    } else if (f < DIN + 2 * CH) {
        int c = f - DIN - CH;
        val = fmaxf(fmaf(h2[(node * GB + bi) * CH + c], st[128 + c], st[192 + c]), 0.f);
    } else if (f < FTOT) {
        int c = f - DIN - 2 * CH;
        float s = b2[c];
#pragma unroll 8
        for (int kk = 0; kk < 64; ++kk)
            s = fmaf(aggRow[kk], W2[kk * 64 + c], s);
        val = fmaxf(s, 0.f);
    }
    if (f < FTOT) flat[(size_t)b * FLATW + k * FTOT + f] = val;
    if (bk == 0 && f >= FTOT && f < FTOT + NB)
        flat[(size_t)(f - FTOT) * FLATW + (FLATW - 1)] = age[f - FTOT];
}

// ---------------- MLP head layer 1: hm += flat @ mW0 (k-split, atomics) ----------------
__global__ void k_head1(const float* __restrict__ flat, const float* __restrict__ mW0,
                        float* hm) {
    int tid = threadIdx.x;
    int j4 = (tid & 31) * 4;       // 32 groups * 4 = 128 cols
    int b0 = (tid >> 5) * 4;       // 8 groups * 4 = 32 rows
    int kbase = blockIdx.x * 64;
    float acc[4][4];
#pragma unroll
    for (int i = 0; i < 4; i++)
#pragma unroll
        for (int jj = 0; jj < 4; jj++) acc[i][jj] = 0.f;
    int kend = FLATW - kbase; if (kend > 64) kend = 64;
    for (int kk = 0; kk < kend; ++kk) {
        int k = kbase + kk;
        float4 w = *(const float4*)(mW0 + (size_t)k * NH + j4);
#pragma unroll
        for (int i = 0; i < 4; i++) {
            float fv = flat[(size_t)(b0 + i) * FLATW + k];
            acc[i][0] = fmaf(fv, w.x, acc[i][0]);
            acc[i][1] = fmaf(fv, w.y, acc[i][1]);
            acc[i][2] = fmaf(fv, w.z, acc[i][2]);
            acc[i][3] = fmaf(fv, w.w, acc[i][3]);
        }
    }
#pragma unroll
    for (int i = 0; i < 4; i++)
#pragma unroll
        for (int jj = 0; jj < 4; jj++)
            atomicAdd(&hm[(size_t)(b0 + i) * NH + j4 + jj], acc[i][jj]);
}

// ---------------- head layer 2 + log_softmax (4-way j-split) ----------------
__global__ void k_head2(const float* __restrict__ hm, const float* __restrict__ mb0,
                        const float* __restrict__ mW1, const float* __restrict__ mb1,
                        float* __restrict__ out) {
    __shared__ float part[256];
    __shared__ float vals[64];
    int tid = threadIdx.x;  // 256 = 32b * 2o * 4q
    int q = tid & 3, o = (tid >> 2) & 1, b = tid >> 3;
    float acc = 0.f;
    for (int j = q * 32; j < q * 32 + 32; ++j) {
        float hv = fmaxf(hm[b * NH + j] + mb0[j], 0.f);
        acc = fmaf(hv, mW1[j * 2 + o], acc);
    }
    part[tid] = acc;
    __syncthreads();
    if (tid < 64) {
        int b2 = tid >> 1, o2 = tid & 1;
        int base = (b2 << 3) + (o2 << 2);
        vals[tid] = part[base] + part[base + 1] + part[base + 2] + part[base + 3] + mb1[o2];
    }
    __syncthreads();
    if (tid < 64) {
        int b2 = tid >> 1;
        float v0 = vals[b2 * 2], v1 = vals[b2 * 2 + 1];
        float m = fmaxf(v0, v1);
        float lse = m + logf(expf(v0 - m) + expf(v1 - m));
        out[tid] = vals[tid] - lse;
    }
}

extern "C" void kernel_launch(void* const* d_in, const int* in_sizes, int n_in,
                              void* d_out, int out_size, void* d_ws, size_t ws_size,
                              hipStream_t stream) {
    const float* x    = (const float*)d_in[0];
    const float* age  = (const float*)d_in[1];
    const float* attr = (const float*)d_in[2];
    const float* W0   = (const float*)d_in[3];
    const float* b0   = (const float*)d_in[4];
    const float* W1   = (const float*)d_in[5];
    const float* b1   = (const float*)d_in[6];
    const float* W2   = (const float*)d_in[7];
    const float* b2   = (const float*)d_in[8];
    const float* g0   = (const float*)d_in[9];
    const float* be0  = (const float*)d_in[10];
    const float* g1   = (const float*)d_in[11];
    const float* be1  = (const float*)d_in[12];
    const float* mW0  = (const float*)d_in[13];
    const float* mb0  = (const float*)d_in[14];
    const float* mW1  = (const float*)d_in[15];
    const float* mb1  = (const float*)d_in[16];
    const int* erow   = (const int*)d_in[17];
    const int* ecol   = (const int*)d_in[18];
    float* out = (float*)d_out;

    // workspace layout (floats); all float4-aligned
    float* ws     = (float*)d_ws;
    float* deg    = ws;                                  // 5008
    float* dinv   = deg + 5008;                          // 5008
    int*   counts = (int*)(dinv + 5008);                 // 5008
    int*   rowptr = counts + 5008;                       // 5008
    int*   cursor = rowptr + 5008;                       // 5008
    int*   perm   = cursor + 5008;                       // 5008
    int*   csr_col= perm + 5008;                         // NEPAD
    float* csr_nv = (float*)(csr_col + NEPAD);           // NEPAD
    float* stats  = csr_nv + NEPAD;                      // 2*32*128 = 8192
    float* st     = stats + 2 * NSLOT * 128;             // 256 (s0,t0,s1,t1)
    float* sc     = st + 256;                            // NG*NN*4 = 160000 (scores)
    int*   order  = (int*)(sc + NB * NN);                // 960
    float* flat   = (float*)(order + 960);               // 32*6241
    float* hm     = flat + (size_t)NB * FLATW;           // 4096
    float* xt     = hm + 4096;                           // (G8,N,4,16)
    float* h1     = xt + (size_t)NB * NN * DIN;          // (G8,N,4,64) each
    float* h2     = h1 + (size_t)NB * NN * CH;
    float* z      = h2 + (size_t)NB * NN * CH;           // NG*NN*4 = 160000

    // graph build: scan+sort+transpose share one dispatch (concurrent roles)
    k_init<<<32, 256, 0, stream>>>(deg, counts, stats, hm, perm);
    k_edges<<<NEB, 256, 0, stream>>>(attr, erow, deg, counts);
    k_phase1<<<2 + (NB * NN + 1023) / 1024, 1024, 0, stream>>>(counts, deg, rowptr, cursor, dinv, perm, x, xt);
    k_build<<<(NE + NN + 1023) / 1024, 1024, 0, stream>>>(erow, ecol, attr, dinv, counts, rowptr, cursor, csr_col, csr_nv);

    const int NBLK = NCHUNK * NG;   // 313 * 8
    // conv0 + conv1 (full gather layers); conv2 replaced by z/score/gather-agg
    k_layer<16, 0, 1><<<NBLK, 256, 0, stream>>>(xt, nullptr, nullptr, nullptr, W0, b0, rowptr, csr_col, csr_nv, dinv, perm, h1, stats);
    k_layer<64, 1, 1><<<NBLK, 256, 0, stream>>>(h1, stats, g0, be0, W1, b1, rowptr, csr_col, csr_nv, dinv, perm, h2, stats + NSLOT * 128);
    k_z<<<ZBLK, 256, 0, stream>>>(h2, stats + NSLOT * 128, g1, be1, W2, z);
    k_score<<<(NN / 4) * NG, 256, 0, stream>>>(z, b2, rowptr, csr_col, csr_nv, dinv, sc);

    // sort-pool (+fused bnfin) + gather (inline agg + deferred GEMM) + head
    k_toppool<<<NB + 1, 1024, 0, stream>>>(sc, order, stats, g0, be0, g1, be1, st);
    k_gather<<<NB * KPOOL, 256, 0, stream>>>(xt, h1, h2, W2, b2, st, age, rowptr, csr_col, csr_nv, dinv, order, flat);
    k_head1<<<(FLATW + 63) / 64, 256, 0, stream>>>(flat, mW0, hm);
    k_head2<<<1, 256, 0, stream>>>(hm, mb0, mW1, mb1, out);
}